// Round 26
// baseline (163.315 us; speedup 1.0000x reference)
//
#include <hip/hip_runtime.h>

#define DD 256
#define HWN 1024
#define NN 32768
#define KK 1024
#define MARGIN 1e-4f
#define FLAGBIT (1 << 30)

// f32-element offsets into d_out (out_size = 16809984 floats):
#define ZQ_OFF   0          // z_q   [32,256,32,32]
#define IDX_OFF  8388608    // idx   [32768]
#define LOSS_OFF 8421376    // loss  [32,32,32,256] (NHWC)

// ws layout (MFMA path; else fp32 fallback):
// [0, 4096)            float e2[1024]
// [4096, 135168)       float z2[32768]
// [135168, 266240)     int   bestIdx[32768]   (FLAGBIT marks near-tie rows)
// [266240, 3411968)    float part[32768][4][3]
// [3411968, 3936256)   ushort Eh2[8][1024*32]  (f16 1024*E, kc-slab swizzled)
// [3936256, 20713472)  ushort Zh[32768][256]   (f16 Z row-major, for k_out)
// [20713472, 37490688) ushort Zh2[8][32768*32] (f16 Z, kc-slab swizzled)
// [37490688, 37752832) u64 bestG[32768]
// [37752832, 37752896) int flagCount
// [37752896, 37883968) int flagList[32768]
#define WS_NEED 38146112

typedef __attribute__((ext_vector_type(8))) _Float16 f16x8;
typedef __attribute__((ext_vector_type(4))) float f32x4;
typedef unsigned long long u64;

__device__ __forceinline__ ushort f2h(float x) {
    _Float16 h = (_Float16)x;                  // RNE
    return *reinterpret_cast<ushort*>(&h);
}
__device__ __forceinline__ float h2f(ushort u) {
    _Float16 h = *reinterpret_cast<_Float16*>(&u);
    return (float)h;
}

// LDS slot16 index for element (row r in 128-tile, k-group kgi) — bank swizzle.
__device__ __forceinline__ int swz(int r, int kgi) {
    return (r << 2) + (kgi ^ (r & 3) ^ ((r >> 2) & 3));
}

// -- fused: E -> Eh2 (swizzled kc-slabs of f16 1024*E) + numpy-exact e2 --
// Slab layout (ushort units): Eh2[kc*32768 + tile*4096 + slot16*8 + j]
__global__ __launch_bounds__(256) void k_prepE2(const float* __restrict__ E,
                                                ushort* __restrict__ Eh2,
                                                float* __restrict__ e2,
                                                int* __restrict__ flagCount) {
    __shared__ float ec[32][257];
    const int g = blockIdx.x;          // 32 blocks x 32 rows
    const int th = threadIdx.x;
    const int n0 = g << 5;
    if (g == 0 && th == 0) *flagCount = 0;
#pragma unroll
    for (int j = 0; j < 32; ++j)
        ec[j][th] = E[(size_t)n0 * DD + (j << 8) + th];
    __syncthreads();
    {
        const int r = th & 31, c = th >> 5;        // c = kc slab
        const int row = n0 + r;
        const int t = row >> 7, rl = row & 127;
        ushort hs[32];
#pragma unroll
        for (int i = 0; i < 32; ++i)
            hs[i] = f2h(__fmul_rn(ec[r][(c << 5) + i], 1024.f));
        ushort* sb = Eh2 + (size_t)c * 32768 + (size_t)t * 4096;
#pragma unroll
        for (int kgi = 0; kgi < 4; ++kgi)
            *reinterpret_cast<f16x8*>(&sb[swz(rl, kgi) << 3]) =
                *reinterpret_cast<f16x8*>(&hs[kgi << 3]);
    }
    // e2: numpy pairwise (validated bit-exact association)
    {
        const int row = th >> 3, j = th & 7;
        const float* a = &ec[row][0];
        float x0 = a[j];
        float r0 = __fmul_rn(x0, x0);
        float x1 = a[128 + j];
        float r1 = __fmul_rn(x1, x1);
#pragma unroll
        for (int i = 8; i < 128; i += 8) {
            float y0 = a[i + j];
            r0 = __fadd_rn(r0, __fmul_rn(y0, y0));
            float y1 = a[128 + i + j];
            r1 = __fadd_rn(r1, __fmul_rn(y1, y1));
        }
#pragma unroll
        for (int m = 1; m <= 4; m <<= 1) {
            r0 = __fadd_rn(r0, __shfl_xor(r0, m));
            r1 = __fadd_rn(r1, __shfl_xor(r1, m));
        }
        if (j == 0) e2[n0 + row] = __fadd_rn(r0, r1);
    }
}

// -- fused: Z transpose -> Zh (row-major) + Zh2 (swizzled slabs) + z2 --
__global__ __launch_bounds__(256) void k_prepZ2(const float* __restrict__ Z,
                                                ushort* __restrict__ Zh,
                                                ushort* __restrict__ Zh2,
                                                float* __restrict__ z2) {
    __shared__ float zc[32][257];      // 32896 B
    const int g = blockIdx.x;          // 1024 blocks: 32 rows each
    const int b = g >> 5;
    const int hw0 = (g & 31) << 5;
    const int th = threadIdx.x;
    const int n0 = (b << 10) + hw0;

#pragma unroll
    for (int j = 0; j < 32; ++j) {
        int li = (j << 8) + th;        // 0..8191
        int d = li >> 5;
        int hl = li & 31;              // 32 consecutive hw = 128B segment
        zc[hl][d] = Z[(size_t)((b << 8) + d) * HWN + hw0 + hl];
    }
    __syncthreads();

    {
        const int r = th & 31, c = th >> 5;        // c = kc slab
        const int n = n0 + r;
        const int t = n >> 7, rl = n & 127;
        ushort hs[32];
#pragma unroll
        for (int i = 0; i < 32; ++i) hs[i] = f2h(zc[r][(c << 5) + i]);
        size_t addr = (size_t)n * DD + (c << 5);
#pragma unroll
        for (int q = 0; q < 4; ++q)
            *reinterpret_cast<f16x8*>(&Zh[addr + (q << 3)]) =
                *reinterpret_cast<f16x8*>(&hs[q << 3]);
        ushort* sb = Zh2 + (size_t)c * 1048576 + (size_t)t * 4096;
#pragma unroll
        for (int kgi = 0; kgi < 4; ++kgi)
            *reinterpret_cast<f16x8*>(&sb[swz(rl, kgi) << 3]) =
                *reinterpret_cast<f16x8*>(&hs[kgi << 3]);
    }

    // z2: numpy pairwise (validated bit-exact structure)
    {
        const int row = th >> 3, j = th & 7;
        const float* a = &zc[row][0];
        float x0 = a[j];
        float r0 = __fmul_rn(x0, x0);
        float x1 = a[128 + j];
        float r1 = __fmul_rn(x1, x1);
#pragma unroll
        for (int i = 8; i < 128; i += 8) {
            float y0 = a[i + j];
            r0 = __fadd_rn(r0, __fmul_rn(y0, y0));
            float y1 = a[128 + i + j];
            r1 = __fadd_rn(r1, __fmul_rn(y1, y1));
        }
#pragma unroll
        for (int m = 1; m <= 4; m <<= 1) {
            r0 = __fadd_rn(r0, __shfl_xor(r0, m));
            r1 = __fadd_rn(r1, __shfl_xor(r1, m));
        }
        if (j == 0) z2[n0 + row] = __fadd_rn(r0, r1);
    }
}

// ---------------- z2 standalone (fallback path only) ----------------
__global__ __launch_bounds__(256) void k_z2(const float* __restrict__ Z,
                                            float* __restrict__ z2) {
    int n = (blockIdx.x << 8) + threadIdx.x;
    int b = n >> 10, hw = n & 1023;
    const float* base = Z + (size_t)(b << 8) * HWN + hw;
    float half_[2];
#pragma unroll
    for (int h = 0; h < 2; ++h) {
        const float* a = base + (size_t)(h << 7) * HWN;
        float r[8];
#pragma unroll
        for (int j = 0; j < 8; ++j) {
            float x = a[(size_t)j * HWN];
            r[j] = __fmul_rn(x, x);
        }
        for (int i = 8; i < 128; i += 8) {
#pragma unroll
            for (int j = 0; j < 8; ++j) {
                float x = a[(size_t)(i + j) * HWN];
                r[j] = __fadd_rn(r[j], __fmul_rn(x, x));
            }
        }
        half_[h] = __fadd_rn(__fadd_rn(__fadd_rn(r[0], r[1]), __fadd_rn(r[2], r[3])),
                             __fadd_rn(__fadd_rn(r[4], r[5]), __fadd_rn(r[6], r[7])));
    }
    z2[n] = __fadd_rn(half_[0], half_[1]);
}

// --- MFMA distance pass: 128 rows x 256 codes, slab staging, wide tile ---
// LDS buf: z[4096 ushorts] + e[8192 ushorts] per double-buffer half.
__device__ __forceinline__ void stage_kc(const ushort* __restrict__ Zs,
                                         const ushort* __restrict__ Es,
                                         ushort* ldsbuf, int rb, int cb, int kc,
                                         int wid, int lane) {
#pragma unroll
    for (int is = 0; is < 6; ++is) {
        const int chunk = wid * 6 + is;      // 0..23 (wave-uniform)
        const ushort* g;
        ushort* l;
        if (chunk < 8) {                     // z: 8 x 1KB
            g = Zs + (size_t)kc * 1048576 + (size_t)rb * 4096 + (chunk << 9) + (lane << 3);
            l = ldsbuf + (chunk << 9);
        } else {                             // e: 16 x 1KB over 2 code tiles
            const int ce = chunk - 8;        // 0..15
            const int et = (cb << 1) + (ce >> 3);
            g = Es + (size_t)kc * 32768 + (size_t)et * 4096 + ((ce & 7) << 9) + (lane << 3);
            l = ldsbuf + 4096 + (ce << 9);
        }
        __builtin_amdgcn_global_load_lds(
            (const __attribute__((address_space(1))) void*)g,
            (__attribute__((address_space(3))) void*)l, 16, 0, 0);
    }
}

__global__ __launch_bounds__(256) void k_dist_mfma(const ushort* __restrict__ Zh2,
                                                   const ushort* __restrict__ Eh2,
                                                   const float* __restrict__ e2,
                                                   float* __restrict__ part) {
    __shared__ ushort lds[2][12288];       // 49152 B double-buffered {z, e}
    float (*red)[2][3] = reinterpret_cast<float (*)[2][3]>(&lds[0][0]);

    const int B = blockIdx.x;              // 1024 blocks = 4 cb x 256 rb
    const int xcd = B & 7;
    const int j = B >> 3;                  // 0..127
    const int cb = j & 3;
    const int rb = (xcd << 5) + (j >> 2);  // 0..255, contiguous per XCD
    const int n0 = rb << 7, c0 = cb << 8;
    const int th = threadIdx.x;
    const int wid = th >> 6, lane = th & 63;
    const int wr = wid >> 1, wc = wid & 1;
    const int fr = lane & 15, kgi = lane >> 4;

    f32x4 acc[4][8];
#pragma unroll
    for (int i = 0; i < 4; ++i)
#pragma unroll
        for (int jj = 0; jj < 8; ++jj) acc[i][jj] = (f32x4){0.f, 0.f, 0.f, 0.f};

    int zoff[4], eoff[8];
#pragma unroll
    for (int mi = 0; mi < 4; ++mi)
        zoff[mi] = swz((wr << 6) + (mi << 4) + fr, kgi) << 4;
#pragma unroll
    for (int ni = 0; ni < 8; ++ni) {
        int code = (wc << 7) + (ni << 4) + fr;         // 0..255 within block
        eoff[ni] = (8192 + ((code >> 7) << 13)) + (swz(code & 127, kgi) << 4);
        // note: byte offset = 4096*2 (z area) + tile*4096*2 + swz*16
    }

    stage_kc(Zh2, Eh2, &lds[0][0], rb, cb, 0, wid, lane);

    for (int kc = 0; kc < 8; ++kc) {
        __builtin_amdgcn_s_barrier();
        if (kc < 7) {
            stage_kc(Zh2, Eh2, &lds[(kc + 1) & 1][0], rb, cb, kc + 1, wid, lane);
            asm volatile("s_waitcnt vmcnt(6)" ::: "memory");
        } else {
            asm volatile("s_waitcnt vmcnt(0)" ::: "memory");
        }
        __builtin_amdgcn_s_barrier();

        const char* bb = (const char*)&lds[kc & 1][0];
        f16x8 za[4], ea[8];
#pragma unroll
        for (int mi = 0; mi < 4; ++mi)
            za[mi] = *reinterpret_cast<const f16x8*>(bb + zoff[mi]);
#pragma unroll
        for (int ni = 0; ni < 8; ++ni)
            ea[ni] = *reinterpret_cast<const f16x8*>(bb + eoff[ni]);
        __builtin_amdgcn_s_setprio(1);
#pragma unroll
        for (int mi = 0; mi < 4; ++mi)
#pragma unroll
            for (int ni = 0; ni < 8; ++ni)
                acc[mi][ni] = __builtin_amdgcn_mfma_f32_16x16x32_f16(za[mi], ea[ni], acc[mi][ni], 0, 0, 0);
        __builtin_amdgcn_s_setprio(0);
    }

    __syncthreads();   // all frag LDS reads consumed -> reuse lds as red

    float e2v[8];
#pragma unroll
    for (int ni = 0; ni < 8; ++ni) e2v[ni] = e2[c0 + (wc << 7) + (ni << 4) + fr];

#pragma unroll
    for (int mi = 0; mi < 4; ++mi) {
#pragma unroll
        for (int jj = 0; jj < 4; ++jj) {
            float m1 = __builtin_inff(), m2 = __builtin_inff(), bi = 3.4e38f;
#pragma unroll
            for (int ni = 0; ni < 8; ++ni) {
                float s = fmaf(-0x1p-9f, acc[mi][ni][jj], e2v[ni]);  // -2*dot, undo x1024
                float c = (float)(c0 + (wc << 7) + (ni << 4) + fr);
                if (s < m1)      { m2 = m1; m1 = s; bi = c; }
                else if (s < m2) { m2 = s; }
            }
#pragma unroll
            for (int m = 1; m <= 8; m <<= 1) {
                float om1 = __shfl_xor(m1, m);
                float om2 = __shfl_xor(m2, m);
                float obi = __shfl_xor(bi, m);
                if (om1 < m1)       { m2 = fminf(m1, om2); m1 = om1; bi = obi; }
                else if (om1 == m1) { bi = fminf(bi, obi); m2 = m1; }
                else                { m2 = fminf(m2, om1); }
            }
            if (fr == 0) {
                int row = (wr << 6) + (mi << 4) + (kgi << 2) + jj;
                red[row][wc][0] = m1; red[row][wc][1] = m2; red[row][wc][2] = bi;
            }
        }
    }
    __syncthreads();
    if (th < 128) {
        // merge wc=0 (codes c0..c0+127) then wc=1 (c0+128..): ascending order
        float M1 = red[th][0][0], M2 = red[th][0][1], I = red[th][0][2];
        float v1 = red[th][1][0], v2 = red[th][1][1], vi = red[th][1][2];
        if (v1 < M1)       { M2 = fminf(M1, v2); M1 = v1; I = vi; }
        else if (v1 == M1) { I = fminf(I, vi); M2 = M1; }
        else               { M2 = fminf(M2, v1); }
        size_t p = ((size_t)(n0 + th) * 4 + cb) * 3;
        part[p] = M1; part[p + 1] = M2; part[p + 2] = I;
    }
}

// -- combine 4 code-slices -> bestIdx (FLAGBIT near-tie) + list + bestG init --
__global__ __launch_bounds__(256) void k_combine(const float* __restrict__ part,
                                                 int* __restrict__ bestIdx,
                                                 int* __restrict__ flagList,
                                                 int* __restrict__ flagCount,
                                                 u64* __restrict__ bestG) {
    int n = (blockIdx.x << 8) + threadIdx.x;
    const float* p = part + (size_t)n * 12;
    float M1 = __builtin_inff(), M2 = __builtin_inff(), I = 3.4e38f;
    for (int c = 0; c < 4; ++c) {
        float v1 = p[c * 3], v2 = p[c * 3 + 1], vi = p[c * 3 + 2];
        if (v1 < M1)       { M2 = fminf(M1, v2); M1 = v1; I = vi; }
        else if (v1 == M1) { I = fminf(I, vi); M2 = M1; }
        else               { M2 = fminf(M2, v1); }
    }
    if (M2 - M1 < MARGIN) {
        bestIdx[n] = (int)I | FLAGBIT;
        bestG[n] = ~0ull;
        int pos = atomicAdd(flagCount, 1);
        flagList[pos] = n;
    } else {
        bestIdx[n] = (int)I;
    }
}

// ---- np-f32-grid re-argmin: (4-row group, code quarter); each E float4
// ---- feeds 4 dot-chains; merge via u64 atomicMin (g>0 always).
__global__ __launch_bounds__(256) void k_refine5(const float* __restrict__ Z,
                                                 const float* __restrict__ E,
                                                 const float* __restrict__ e2,
                                                 const float* __restrict__ z2,
                                                 const int* __restrict__ flagList,
                                                 const int* __restrict__ flagCount,
                                                 u64* __restrict__ bestG) {
    __shared__ float zsh[4][DD];
    __shared__ float gbv[16][4];
    __shared__ int gbi[16][4];
    __shared__ int rown[4];
    const int th = threadIdx.x;
    const int g = th >> 4;             // code group 0..15
    const int l = th & 15;             // lane in group
    const int cnt = *flagCount;
    const int items = ((cnt + 3) >> 2) << 2;

    for (int jj = blockIdx.x; jj < items; jj += (int)gridDim.x) {
        const int gi = jj >> 2;
        const int q = jj & 3;
        __syncthreads();
        if (th < 4) {
            int fi = (gi << 2) + th;
            if (fi >= cnt) fi = cnt - 1;   // duplicate row: identical result
            rown[th] = flagList[fi];
        }
        __syncthreads();
#pragma unroll
        for (int r = 0; r < 4; ++r) {
            int n = rown[r];
            zsh[r][th] = Z[(size_t)(((n >> 10) << 8) + th) * HWN + (n & 1023)];
        }
        __syncthreads();
        float zr[4][16];
#pragma unroll
        for (int r = 0; r < 4; ++r)
#pragma unroll
            for (int jq = 0; jq < 16; ++jq) zr[r][jq] = zsh[r][(l << 4) + jq];
        float z2v[4];
#pragma unroll
        for (int r = 0; r < 4; ++r) z2v[r] = z2[rown[r]];
        float gbest[4];
        int bi[4];
#pragma unroll
        for (int r = 0; r < 4; ++r) { gbest[r] = __builtin_inff(); bi[r] = 0; }

        const int base = q << 8;
        for (int it = 0; it < 4; ++it) {
#pragma unroll
            for (int u = 0; u < 4; ++u) {      // ascending code order
                const int c = base + (it << 6) + (u << 4) + g;
                const float* er = &E[(size_t)c * DD + (l << 4)];
                float4 a0 = *reinterpret_cast<const float4*>(er);
                float4 a1 = *reinterpret_cast<const float4*>(er + 4);
                float4 a2 = *reinterpret_cast<const float4*>(er + 8);
                float4 a3 = *reinterpret_cast<const float4*>(er + 12);
                double dots[4];
#pragma unroll
                for (int r = 0; r < 4; ++r) {
                    double s0 = (double)a0.x * zr[r][0]  + (double)a0.y * zr[r][1]
                              + (double)a0.z * zr[r][2]  + (double)a0.w * zr[r][3];
                    double s1 = (double)a1.x * zr[r][4]  + (double)a1.y * zr[r][5]
                              + (double)a1.z * zr[r][6]  + (double)a1.w * zr[r][7];
                    double s2 = (double)a2.x * zr[r][8]  + (double)a2.y * zr[r][9]
                              + (double)a2.z * zr[r][10] + (double)a2.w * zr[r][11];
                    double s3 = (double)a3.x * zr[r][12] + (double)a3.y * zr[r][13]
                              + (double)a3.z * zr[r][14] + (double)a3.w * zr[r][15];
                    dots[r] = (s0 + s1) + (s2 + s3);
                }
#pragma unroll
                for (int m = 1; m <= 8; m <<= 1) {
#pragma unroll
                    for (int r = 0; r < 4; ++r)
                        dots[r] += __shfl_xor(dots[r], m);
                }
                if (l == 0) {
#pragma unroll
                    for (int r = 0; r < 4; ++r) {
                        float cc = (float)dots[r];
                        float t2 = __fmul_rn(2.0f, cc);
                        float gg = __fsub_rn(__fadd_rn(z2v[r], e2[c]), t2);
                        if (gg < gbest[r]) { gbest[r] = gg; bi[r] = c; }
                    }
                }
            }
        }
        if (l == 0) {
#pragma unroll
            for (int r = 0; r < 4; ++r) { gbv[g][r] = gbest[r]; gbi[g][r] = bi[r]; }
        }
        __syncthreads();
        if (th < 4) {
            const int r = th;
            float best = gbv[0][r]; int bbi = gbi[0][r];
            for (int qq = 1; qq < 16; ++qq) {
                float v = gbv[qq][r]; int vi = gbi[qq][r];
                if (v < best || (v == best && vi < bbi)) { best = v; bbi = vi; }
            }
            u64 pack = ((u64)__float_as_uint(best) << 32) | (unsigned)bbi;
            atomicMin(&bestG[rown[r]], pack);
        }
    }
}

// ======== fp32 fallback distance pass (used if ws too small) ========
#define UPD(m1, m2, i1, s, k)                            \
    do {                                                 \
        if ((s) < (m1)) { m2 = m1; m1 = (s); i1 = (k); } \
        else if ((s) < (m2)) { m2 = (s); }               \
    } while (0)

#define FMAJ(j, EV, C)                                   \
    acc[0][j] = fmaf(z4.x, EV.C, acc[0][j]);             \
    acc[1][j] = fmaf(z4.y, EV.C, acc[1][j]);             \
    acc[2][j] = fmaf(z4.z, EV.C, acc[2][j]);             \
    acc[3][j] = fmaf(z4.w, EV.C, acc[3][j]);

#define UROUND(u, C)                                                          \
    {                                                                         \
        float4 z4 = *reinterpret_cast<const float4*>(&zs[dq + u][ty4]);       \
        FMAJ(0, e0, C) FMAJ(1, e1, C) FMAJ(2, e2v, C) FMAJ(3, e3, C)          \
        FMAJ(4, e4, C) FMAJ(5, e5, C) FMAJ(6, e6, C) FMAJ(7, e7, C)           \
    }

__global__ __launch_bounds__(256, 3) void k_dist_f32(const float* __restrict__ Z,
                                                     const float* __restrict__ E,
                                                     const float* __restrict__ e2,
                                                     int* __restrict__ bestIdx) {
    __shared__ float zs[64][68];
    __shared__ float es[128][68];
    const int th = threadIdx.x;
    const int n0 = blockIdx.x << 6;
    const int b = n0 >> 10;
    const int hw0 = n0 & 1023;
    const int tx = th & 15;
    const int ty = th >> 4;
    const int ty4 = ty << 2;
    float m1[4], m2[4];
    int idx[4];
#pragma unroll
    for (int i = 0; i < 4; ++i) { m1[i] = __builtin_inff(); m2[i] = __builtin_inff(); idx[i] = 0; }
    for (int ct = 0; ct < 8; ++ct) {
        float acc[4][8];
#pragma unroll
        for (int i = 0; i < 4; ++i)
#pragma unroll
            for (int j = 0; j < 8; ++j) acc[i][j] = 0.f;
        for (int dc = 0; dc < 4; ++dc) {
            __syncthreads();
#pragma unroll
            for (int j = 0; j < 4; ++j) {
                int i4 = (j << 8) + th;
                int dd = i4 >> 4;
                int rr = (i4 & 15) << 2;
                *reinterpret_cast<float4*>(&zs[dd][rr]) =
                    *reinterpret_cast<const float4*>(
                        &Z[(size_t)((b << 8) + (dc << 6) + dd) * HWN + hw0 + rr]);
            }
#pragma unroll
            for (int j = 0; j < 8; ++j) {
                int i4 = (j << 8) + th;
                int c = i4 >> 4;
                int d4 = (i4 & 15) << 2;
                *reinterpret_cast<float4*>(&es[c][d4]) =
                    *reinterpret_cast<const float4*>(
                        &E[(size_t)((ct << 7) + c) * DD + (dc << 6) + d4]);
            }
            __syncthreads();
#pragma unroll
            for (int dq = 0; dq < 64; dq += 4) {
                float4 e0 = *reinterpret_cast<const float4*>(&es[tx][dq]);
                float4 e1 = *reinterpret_cast<const float4*>(&es[tx + 16][dq]);
                float4 e2v = *reinterpret_cast<const float4*>(&es[tx + 32][dq]);
                float4 e3 = *reinterpret_cast<const float4*>(&es[tx + 48][dq]);
                float4 e4 = *reinterpret_cast<const float4*>(&es[tx + 64][dq]);
                float4 e5 = *reinterpret_cast<const float4*>(&es[tx + 80][dq]);
                float4 e6 = *reinterpret_cast<const float4*>(&es[tx + 96][dq]);
                float4 e7 = *reinterpret_cast<const float4*>(&es[tx + 112][dq]);
                UROUND(0, x)
                UROUND(1, y)
                UROUND(2, z)
                UROUND(3, w)
            }
        }
#pragma unroll
        for (int j = 0; j < 8; ++j) {
            int c = (ct << 7) + tx + (j << 4);
            float en = e2[c];
#pragma unroll
            for (int i = 0; i < 4; ++i) {
                float s = fmaf(-2.f, acc[i][j], en);
                UPD(m1[i], m2[i], idx[i], s, c);
            }
        }
    }
    __syncthreads();
    float* red = &es[0][0];
#pragma unroll
    for (int i = 0; i < 4; ++i) {
        int r = ty4 + i;
        int base = ((r << 4) + tx) * 3;
        red[base] = m1[i]; red[base + 1] = m2[i]; red[base + 2] = (float)idx[i];
    }
    __syncthreads();
    if (th < 64) {
        float M1 = __builtin_inff(), M2 = __builtin_inff(), I = 3.4e38f;
        for (int t = 0; t < 16; ++t) {
            int base = ((th << 4) + t) * 3;
            float v1 = red[base], v2 = red[base + 1], vi = red[base + 2];
            if (v1 < M1)       { M2 = fminf(M1, v2); M1 = v1; I = vi; }
            else if (v1 == M1) { I = fminf(I, vi); M2 = fminf(M2, v1); M2 = fminf(M2, v2); }
            else               { M2 = fminf(M2, v1); }
        }
        int id = (int)I;
        bestIdx[n0 + th] = (M2 - M1 < MARGIN) ? (id | FLAGBIT) : id;
    }
}

// -------- fallback-path refine (FLAGBIT scan, unchanged semantics) --------
__global__ __launch_bounds__(64) void k_refine(const float* __restrict__ Z,
                                               const float* __restrict__ E,
                                               const float* __restrict__ e2,
                                               const float* __restrict__ z2,
                                               int* __restrict__ bestIdx) {
    __shared__ float zr[DD];
    const int l = threadIdx.x;
    for (int i = 0; i < 16; ++i) {
        int n = (blockIdx.x << 4) + i;
        if (!(bestIdx[n] & FLAGBIT)) continue;
        int b = n >> 10, hw = n & 1023;
        __syncthreads();
#pragma unroll
        for (int j = 0; j < 4; ++j)
            zr[(l << 2) + j] = Z[(size_t)((b << 8) + (l << 2) + j) * HWN + hw];
        __syncthreads();
        const float z2v = z2[n];
        float gbest = __builtin_inff();
        int bi = KK;
        for (int kk = 0; kk < 16; ++kk) {
            int k = (kk << 6) + l;
            double dot = 0.0;
            for (int d = 0; d < DD; d += 4) {
                float4 e4 = *reinterpret_cast<const float4*>(&E[(size_t)k * DD + d]);
                dot += (double)e4.x * zr[d]     + (double)e4.y * zr[d + 1]
                     + (double)e4.z * zr[d + 2] + (double)e4.w * zr[d + 3];
            }
            float c = (float)dot;
            float t = __fmul_rn(2.0f, c);
            float gg = __fsub_rn(__fadd_rn(z2v, e2[k]), t);
            if (gg < gbest) { gbest = gg; bi = k; }
        }
#pragma unroll
        for (int off = 32; off > 0; off >>= 1) {
            float og = __shfl_down(gbest, off);
            int oi = __shfl_down(bi, off);
            if (og < gbest || (og == gbest && oi < bi)) { gbest = og; bi = oi; }
        }
        if (l == 0) bestIdx[n] = bi;
    }
}

// -------- outputs (MFMA path): idx (FLAGBIT->bestG), loss from Zh, z_q --------
__global__ __launch_bounds__(256) void k_out(const ushort* __restrict__ Zh,
                                             const float* __restrict__ E,
                                             const int* __restrict__ bestIdx,
                                             const u64* __restrict__ bestG,
                                             float* __restrict__ out) {
    __shared__ int idxs[64];
    __shared__ float es[64][68];
    const int th = threadIdx.x;
    const int n0 = blockIdx.x << 6;    // 512 blocks, 64 rows each
    const int b = n0 >> 10;
    const int hw0 = n0 & 1023;

    if (th < 64) {
        int n = n0 + th;
        int v = bestIdx[n];
        int id = (v & FLAGBIT) ? (int)(unsigned)(bestG[n] & 1023ull) : (v & 1023);
        idxs[th] = id;
        out[IDX_OFF + n] = (float)id;
    }
    __syncthreads();

    // loss (NHWC): lane-adjacent float4 writes; z from Zh (f16, err << threshold)
#pragma unroll
    for (int j = 0; j < 16; ++j) {
        int i4 = (j << 8) + th;
        int r = i4 >> 6;
        int f = (i4 & 63) << 2;
        int n = n0 + r;
        float4 e4 = *reinterpret_cast<const float4*>(&E[(size_t)idxs[r] * DD + f]);
        ushort4 zu = *reinterpret_cast<const ushort4*>(&Zh[(size_t)n * DD + f]);
        float4 o;
        float t;
        t = e4.x - h2f(zu.x); o.x = t * t;
        t = e4.y - h2f(zu.y); o.y = t * t;
        t = e4.z - h2f(zu.z); o.z = t * t;
        t = e4.w - h2f(zu.w); o.w = t * t;
        *reinterpret_cast<float4*>(&out[LOSS_OFF + (size_t)n * DD + f]) = o;
    }

    // z_q (NCHW): stage gathered E rows per dc-chunk, write hw-coalesced
    for (int dc = 0; dc < 4; ++dc) {
        __syncthreads();
        {
            const int r = th >> 2, qd = (th & 3) << 4;
            const float* er = &E[(size_t)idxs[r] * DD + (dc << 6) + qd];
#pragma unroll
            for (int v = 0; v < 4; ++v)
                *reinterpret_cast<float4*>(&es[r][qd + (v << 2)]) =
                    *reinterpret_cast<const float4*>(er + (v << 2));
        }
        __syncthreads();
#pragma unroll
        for (int j = 0; j < 16; ++j) {
            int li = (j << 8) + th;
            int dd = li >> 6;
            int r = li & 63;
            out[ZQ_OFF + (size_t)((b << 8) + (dc << 6) + dd) * HWN + hw0 + r] =
                es[r][dd];
        }
    }
}

// -------- outputs (fallback path): reads Z --------
__global__ __launch_bounds__(256) void k_out_f32(const float* __restrict__ Z,
                                                 const float* __restrict__ E,
                                                 const int* __restrict__ bestIdx,
                                                 float* __restrict__ out) {
    __shared__ float zc[64][68];
    __shared__ int idxs[64];
    const int th = threadIdx.x;
    const int n0 = blockIdx.x << 6;
    const int b = n0 >> 10;
    const int hw0 = n0 & 1023;

    if (th < 64) {
        int id = bestIdx[n0 + th] & 1023;
        idxs[th] = id;
        out[IDX_OFF + n0 + th] = (float)id;
    }
    __syncthreads();

    for (int dc = 0; dc < 4; ++dc) {
        __syncthreads();
#pragma unroll
        for (int j = 0; j < 16; ++j) {
            int li = (j << 8) + th;
            int dd = li >> 6;
            int r = li & 63;
            zc[r][dd] = Z[(size_t)((b << 8) + (dc << 6) + dd) * HWN + hw0 + r];
        }
        __syncthreads();
#pragma unroll
        for (int j = 0; j < 4; ++j) {
            int i4 = (j << 8) + th;
            int r = i4 >> 4;
            int f = (i4 & 15) << 2;
            float4 e4 = *reinterpret_cast<const float4*>(
                &E[(size_t)idxs[r] * DD + (dc << 6) + f]);
            float4 z4 = *reinterpret_cast<const float4*>(&zc[r][f]);
            float4 o;
            o.x = (e4.x - z4.x) * (e4.x - z4.x);
            o.y = (e4.y - z4.y) * (e4.y - z4.y);
            o.z = (e4.z - z4.z) * (e4.z - z4.z);
            o.w = (e4.w - z4.w) * (e4.w - z4.w);
            *reinterpret_cast<float4*>(
                &out[LOSS_OFF + (size_t)(n0 + r) * DD + (dc << 6) + f]) = o;
        }
#pragma unroll
        for (int j = 0; j < 16; ++j) {
            int li = (j << 8) + th;
            int dd = li >> 6;
            int r = li & 63;
            out[ZQ_OFF + (size_t)((b << 8) + (dc << 6) + dd) * HWN + hw0 + r] =
                E[(size_t)idxs[r] * DD + (dc << 6) + dd];
        }
    }
}

extern "C" void kernel_launch(void* const* d_in, const int* in_sizes, int n_in,
                              void* d_out, int out_size, void* d_ws, size_t ws_size,
                              hipStream_t stream) {
    const float* Z = (const float*)d_in[0];           // [32,256,32,32] f32
    const float* E = (const float*)d_in[1];           // [1024,256] f32
    float* out = (float*)d_out;
    char* ws = (char*)d_ws;
    float* e2 = (float*)ws;
    float* z2 = (float*)(ws + 4096);
    int* bestIdx = (int*)(ws + 135168);

    if (ws_size >= WS_NEED) {
        float* part = (float*)(ws + 266240);
        ushort* Eh2 = (ushort*)(ws + 3411968);
        ushort* Zh = (ushort*)(ws + 3936256);
        ushort* Zh2 = (ushort*)(ws + 20713472);
        u64* bestG = (u64*)(ws + 37490688);
        int* flagCount = (int*)(ws + 37752832);
        int* flagList = (int*)(ws + 37752896);
        k_prepE2<<<32, 256, 0, stream>>>(E, Eh2, e2, flagCount);
        k_prepZ2<<<1024, 256, 0, stream>>>(Z, Zh, Zh2, z2);
        k_dist_mfma<<<1024, 256, 0, stream>>>(Zh2, Eh2, e2, part);
        k_combine<<<NN / 256, 256, 0, stream>>>(part, bestIdx, flagList, flagCount, bestG);
        k_refine5<<<2048, 256, 0, stream>>>(Z, E, e2, z2, flagList, flagCount, bestG);
        k_out<<<NN / 64, 256, 0, stream>>>(Zh, E, bestIdx, bestG, out);
    } else {
        k_z2<<<NN / 256, 256, 0, stream>>>(Z, z2);
        k_prepE2<<<32, 256, 0, stream>>>(E, (ushort*)(ws + 266240), e2, (int*)(ws + 266240 + 524288));
        k_dist_f32<<<NN / 64, 256, 0, stream>>>(Z, E, e2, bestIdx);
        k_refine<<<NN / 16, 64, 0, stream>>>(Z, E, e2, z2, bestIdx);
        k_out_f32<<<NN / 64, 256, 0, stream>>>(Z, E, bestIdx, out);
    }
}

// Round 27
// 137.397 us; speedup vs baseline: 1.1886x; 1.1886x over previous
//
#include <hip/hip_runtime.h>

#define DD 256
#define HWN 1024
#define NN 32768
#define KK 1024
#define MARGIN 1e-4f
#define FLAGBIT (1 << 30)

// f32-element offsets into d_out (out_size = 16809984 floats):
#define ZQ_OFF   0          // z_q   [32,256,32,32]
#define IDX_OFF  8388608    // idx   [32768]
#define LOSS_OFF 8421376    // loss  [32,32,32,256] (NHWC)

// ws layout (MFMA path needs WS_NEED bytes; else fp32 fallback):
// [0, 4096)            float e2[1024]
// [4096, 135168)       float z2[32768]
// [135168, 266240)     int   bestIdx[32768]
// [266240, 3411968)    float part[32768][8][3]
// [3411968, 3936256)   ushort Eh[1024][256]   (f16 of 1024*E)
// [4460544, 21237760)  ushort Zh[32768][256]  (f16 of Z, [n][d])
// [21237760, 21499904) ull bestG[32768]       (packed g|idx atomicMin merge)
// [38014976, 38015040) int flagCount
// [38015040, 38146112) int flagList[32768]
#define WS_NEED 38146112

typedef __attribute__((ext_vector_type(8))) _Float16 f16x8;
typedef __attribute__((ext_vector_type(4))) float f32x4;
typedef unsigned long long u64;

__device__ __forceinline__ ushort f2h(float x) {
    _Float16 h = (_Float16)x;                  // RNE
    return *reinterpret_cast<ushort*>(&h);
}
__device__ __forceinline__ float h2f(ushort u) {
    _Float16 h = *reinterpret_cast<_Float16*>(&u);
    return (float)h;
}

// LDS slot16 index for element (row r, k-group kgi) — bank-spread swizzle.
__device__ __forceinline__ int swz(int r, int kgi) {
    return (r << 2) + (kgi ^ (r & 3) ^ ((r >> 2) & 3));
}

// -- e2[k]: numpy-exact f32 codebook norms, parallel (8 lanes x 2 chains/row) --
__global__ __launch_bounds__(256) void k_e2(const float* __restrict__ E,
                                            float* __restrict__ e2) {
    const int th = threadIdx.x;
    const int row = (blockIdx.x << 5) + (th >> 3);   // 32 rows/block, 32 blocks
    const int j = th & 7;
    const float* a = E + (size_t)row * DD;
    float x0 = a[j];
    float r0 = __fmul_rn(x0, x0);
    float x1 = a[128 + j];
    float r1 = __fmul_rn(x1, x1);
#pragma unroll
    for (int i = 8; i < 128; i += 8) {
        float y0 = a[i + j];
        r0 = __fadd_rn(r0, __fmul_rn(y0, y0));
        float y1 = a[128 + i + j];
        r1 = __fadd_rn(r1, __fmul_rn(y1, y1));
    }
#pragma unroll
    for (int m = 1; m <= 4; m <<= 1) {
        r0 = __fadd_rn(r0, __shfl_xor(r0, m));
        r1 = __fadd_rn(r1, __shfl_xor(r1, m));
    }
    if (j == 0) e2[row] = __fadd_rn(r0, r1);
}

// -- fused: Z transpose (32-row tiles, 128B segments) -> Zh f16 + parallel z2 --
__global__ __launch_bounds__(256) void k_prepZ2(const float* __restrict__ Z,
                                                ushort* __restrict__ Zh,
                                                float* __restrict__ z2) {
    __shared__ float zc[32][257];      // 32896 B
    const int g = blockIdx.x;          // 1024 blocks: 32 rows each
    const int b = g >> 5;
    const int hw0 = (g & 31) << 5;
    const int th = threadIdx.x;
    const int n0 = (b << 10) + hw0;

#pragma unroll
    for (int j = 0; j < 32; ++j) {
        int li = (j << 8) + th;        // 0..8191
        int d = li >> 5;
        int hl = li & 31;              // 32 consecutive hw = 128B segment
        zc[hl][d] = Z[(size_t)((b << 8) + d) * HWN + hw0 + hl];
    }
    __syncthreads();

    // f16 (RNE), [n][d] layout, 64B/thread contiguous
    {
        int r = th >> 3, c = th & 7;
        ushort hs[32];
#pragma unroll
        for (int i = 0; i < 32; ++i) hs[i] = f2h(zc[r][(c << 5) + i]);
        size_t addr = (size_t)(n0 + r) * DD + (c << 5);
#pragma unroll
        for (int q = 0; q < 4; ++q)
            *reinterpret_cast<f16x8*>(&Zh[addr + (q << 3)]) =
                *reinterpret_cast<f16x8*>(&hs[q << 3]);
    }

    // z2: numpy pairwise, parallel (validated bit-exact structure)
    {
        const int row = th >> 3, j = th & 7;
        const float* a = &zc[row][0];
        float x0 = a[j];
        float r0 = __fmul_rn(x0, x0);
        float x1 = a[128 + j];
        float r1 = __fmul_rn(x1, x1);
#pragma unroll
        for (int i = 8; i < 128; i += 8) {
            float y0 = a[i + j];
            r0 = __fadd_rn(r0, __fmul_rn(y0, y0));
            float y1 = a[128 + i + j];
            r1 = __fadd_rn(r1, __fmul_rn(y1, y1));
        }
#pragma unroll
        for (int m = 1; m <= 4; m <<= 1) {
            r0 = __fadd_rn(r0, __shfl_xor(r0, m));
            r1 = __fadd_rn(r1, __shfl_xor(r1, m));
        }
        if (j == 0) z2[n0 + row] = __fadd_rn(r0, r1);
    }
}

// ---------------- z2 standalone (fallback path only) ----------------
__global__ __launch_bounds__(256) void k_z2(const float* __restrict__ Z,
                                            float* __restrict__ z2) {
    int n = (blockIdx.x << 8) + threadIdx.x;
    int b = n >> 10, hw = n & 1023;
    const float* base = Z + (size_t)(b << 8) * HWN + hw;
    float half_[2];
#pragma unroll
    for (int h = 0; h < 2; ++h) {
        const float* a = base + (size_t)(h << 7) * HWN;
        float r[8];
#pragma unroll
        for (int j = 0; j < 8; ++j) {
            float x = a[(size_t)j * HWN];
            r[j] = __fmul_rn(x, x);
        }
        for (int i = 8; i < 128; i += 8) {
#pragma unroll
            for (int j = 0; j < 8; ++j) {
                float x = a[(size_t)(i + j) * HWN];
                r[j] = __fadd_rn(r[j], __fmul_rn(x, x));
            }
        }
        half_[h] = __fadd_rn(__fadd_rn(__fadd_rn(r[0], r[1]), __fadd_rn(r[2], r[3])),
                             __fadd_rn(__fadd_rn(r[4], r[5]), __fadd_rn(r[6], r[7])));
    }
    z2[n] = __fadd_rn(half_[0], half_[1]);
}

// ------- prep: E -> Eh f16 of 1024*E (+ zero flag counter) -------
__global__ __launch_bounds__(256) void k_prepE(const float* __restrict__ E,
                                               ushort* __restrict__ Eh,
                                               int* __restrict__ flagCount) {
    if (blockIdx.x == 0 && threadIdx.x == 0) *flagCount = 0;
    int i4 = (blockIdx.x << 8) + threadIdx.x;        // 0..65535 float4s
    float4 v = *reinterpret_cast<const float4*>(&E[(size_t)i4 << 2]);
    v.x *= 1024.f; v.y *= 1024.f; v.z *= 1024.f; v.w *= 1024.f;   // exact
    ushort4 h;
    h.x = f2h(v.x); h.y = f2h(v.y); h.z = f2h(v.z); h.w = f2h(v.w);
    *reinterpret_cast<ushort4*>(&Eh[(size_t)i4 << 2]) = h;
}

// --- MFMA distance pass: r16 structure, LDS-reuse epilogue -> 5 blocks/CU ---
__device__ __forceinline__ void stage_kc(const ushort* __restrict__ Zh,
                                         const ushort* __restrict__ Eh,
                                         ushort* ldsbuf, int n0, int c0, int kc,
                                         int wid, int lane) {
#pragma unroll
    for (int is = 0; is < 4; ++is) {
        const int chunk = (wid << 2) + is;   // 0..15 (wave-uniform)
        const int arr = chunk >> 3;          // 0: zh, 1: eh
        const int cb8 = chunk & 7;           // chunk within array
        const int s = (cb8 << 6) + lane;     // slot16 this lane fills
        const int r = s >> 2;
        const int kgi = (s & 3) ^ (r & 3) ^ ((r >> 2) & 3);   // inverse swizzle
        const ushort* g = (arr == 0) ? Zh + (size_t)(n0 + r) * DD
                                     : Eh + (size_t)(c0 + r) * DD;
        g += (kc << 5) + (kgi << 3);
        ushort* l = ldsbuf + arr * 4096 + (cb8 << 9);
        __builtin_amdgcn_global_load_lds(
            (const __attribute__((address_space(1))) void*)g,
            (__attribute__((address_space(3))) void*)l, 16, 0, 0);
    }
}

__global__ __launch_bounds__(256) void k_dist_mfma(const ushort* __restrict__ Zh,
                                                   const ushort* __restrict__ Eh,
                                                   const float* __restrict__ e2,
                                                   float* __restrict__ part) {
    __shared__ ushort lds[2][2][4096];     // 32768 B total -> 5 blocks/CU
    float (*red)[2][3] = reinterpret_cast<float (*)[2][3]>(&lds[0][0][0]);

    const int B = blockIdx.x;              // 2048 blocks
    const int xcd = B & 7;
    const int j = B >> 3;                  // 0..255
    const int cb = j & 7;
    const int rb = (xcd << 5) + (j >> 3);
    const int n0 = rb << 7, c0 = cb << 7;
    const int th = threadIdx.x;
    const int wid = th >> 6, lane = th & 63;
    const int wr = wid >> 1, wc = wid & 1;
    const int fr = lane & 15, kgi = lane >> 4;

    f32x4 acc[4][4];
#pragma unroll
    for (int i = 0; i < 4; ++i)
#pragma unroll
        for (int jj = 0; jj < 4; ++jj) acc[i][jj] = (f32x4){0.f, 0.f, 0.f, 0.f};

    int zoff[4], eoff[4];
#pragma unroll
    for (int mi = 0; mi < 4; ++mi)
        zoff[mi] = swz((wr << 6) + (mi << 4) + fr, kgi) << 4;
#pragma unroll
    for (int ni = 0; ni < 4; ++ni)
        eoff[ni] = swz((wc << 6) + (ni << 4) + fr, kgi) << 4;

    stage_kc(Zh, Eh, &lds[0][0][0], n0, c0, 0, wid, lane);

    for (int kc = 0; kc < 8; ++kc) {
        __builtin_amdgcn_s_barrier();
        if (kc < 7) {
            stage_kc(Zh, Eh, &lds[(kc + 1) & 1][0][0], n0, c0, kc + 1, wid, lane);
            asm volatile("s_waitcnt vmcnt(4)" ::: "memory");
        } else {
            asm volatile("s_waitcnt vmcnt(0)" ::: "memory");
        }
        __builtin_amdgcn_s_barrier();

        const char* zb  = (const char*)&lds[kc & 1][0][0];
        const char* ebh = (const char*)&lds[kc & 1][1][0];
        f16x8 za[4], ea[4];
#pragma unroll
        for (int mi = 0; mi < 4; ++mi)
            za[mi] = *reinterpret_cast<const f16x8*>(zb + zoff[mi]);
#pragma unroll
        for (int ni = 0; ni < 4; ++ni)
            ea[ni] = *reinterpret_cast<const f16x8*>(ebh + eoff[ni]);
        __builtin_amdgcn_s_setprio(1);
#pragma unroll
        for (int mi = 0; mi < 4; ++mi)
#pragma unroll
            for (int ni = 0; ni < 4; ++ni)
                acc[mi][ni] = __builtin_amdgcn_mfma_f32_16x16x32_f16(za[mi], ea[ni], acc[mi][ni], 0, 0, 0);
        __builtin_amdgcn_s_setprio(0);
    }

    __syncthreads();   // all frag LDS reads consumed -> safe to reuse lds as red

    float e2v[4];
#pragma unroll
    for (int ni = 0; ni < 4; ++ni) e2v[ni] = e2[c0 + (wc << 6) + (ni << 4) + fr];

#pragma unroll
    for (int mi = 0; mi < 4; ++mi) {
#pragma unroll
        for (int jj = 0; jj < 4; ++jj) {
            float m1 = __builtin_inff(), m2 = __builtin_inff(), bi = 3.4e38f;
#pragma unroll
            for (int ni = 0; ni < 4; ++ni) {
                float s = fmaf(-0x1p-9f, acc[mi][ni][jj], e2v[ni]);  // -2*dot, undo x1024
                float c = (float)(c0 + (wc << 6) + (ni << 4) + fr);
                if (s < m1)      { m2 = m1; m1 = s; bi = c; }
                else if (s < m2) { m2 = s; }
            }
#pragma unroll
            for (int m = 1; m <= 8; m <<= 1) {
                float om1 = __shfl_xor(m1, m);
                float om2 = __shfl_xor(m2, m);
                float obi = __shfl_xor(bi, m);
                if (om1 < m1)       { m2 = fminf(m1, om2); m1 = om1; bi = obi; }
                else if (om1 == m1) { bi = fminf(bi, obi); m2 = m1; }
                else                { m2 = fminf(m2, om1); }
            }
            if (fr == 0) {
                int row = (wr << 6) + (mi << 4) + (kgi << 2) + jj;
                red[row][wc][0] = m1; red[row][wc][1] = m2; red[row][wc][2] = bi;
            }
        }
    }
    __syncthreads();
    if (th < 128) {
        float M1 = red[th][0][0], M2 = red[th][0][1], I = red[th][0][2];
        float v1 = red[th][1][0], v2 = red[th][1][1], vi = red[th][1][2];
        if (v1 < M1)       { M2 = fminf(M1, v2); M1 = v1; I = vi; }
        else if (v1 == M1) { I = fminf(I, vi); M2 = M1; }
        else               { M2 = fminf(M2, v1); }
        size_t p = ((size_t)(n0 + th) * 8 + cb) * 3;
        part[p] = M1; part[p + 1] = M2; part[p + 2] = I;
    }
}

// -- combine 8 code-slices -> bestIdx + compacted near-tie list + bestG init --
__global__ __launch_bounds__(256) void k_combine(const float* __restrict__ part,
                                                 int* __restrict__ bestIdx,
                                                 int* __restrict__ flagList,
                                                 int* __restrict__ flagCount,
                                                 u64* __restrict__ bestG) {
    int n = (blockIdx.x << 8) + threadIdx.x;
    const float* p = part + (size_t)n * 24;
    float M1 = __builtin_inff(), M2 = __builtin_inff(), I = 3.4e38f;
    for (int c = 0; c < 8; ++c) {
        float v1 = p[c * 3], v2 = p[c * 3 + 1], vi = p[c * 3 + 2];
        if (v1 < M1)       { M2 = fminf(M1, v2); M1 = v1; I = vi; }
        else if (v1 == M1) { I = fminf(I, vi); M2 = M1; }
        else               { M2 = fminf(M2, v1); }
    }
    bestIdx[n] = (int)I;
    if (M2 - M1 < MARGIN) {
        bestG[n] = ~0ull;
        int pos = atomicAdd(flagCount, 1);
        flagList[pos] = n;
    }
}

// ---- np-f32-grid re-argmin: item = (4-row group, code quarter); each E
// ---- float4 feeds 4 dot-chains; merge via u64 atomicMin (g>0 always).
__global__ __launch_bounds__(256) void k_refine5(const float* __restrict__ Z,
                                                 const float* __restrict__ E,
                                                 const float* __restrict__ e2,
                                                 const float* __restrict__ z2,
                                                 const int* __restrict__ flagList,
                                                 const int* __restrict__ flagCount,
                                                 u64* __restrict__ bestG) {
    __shared__ float zsh[4][DD];
    __shared__ float gbv[16][4];
    __shared__ int gbi[16][4];
    __shared__ int rown[4];
    const int th = threadIdx.x;
    const int g = th >> 4;             // code group 0..15
    const int l = th & 15;             // lane in group
    const int cnt = *flagCount;
    const int items = ((cnt + 3) >> 2) << 2;   // 4 quarters per 4-row group

    for (int jj = blockIdx.x; jj < items; jj += (int)gridDim.x) {
        const int gi = jj >> 2;        // row group
        const int q = jj & 3;          // code quarter
        __syncthreads();               // protect shared state from prev item
        if (th < 4) {
            int fi = (gi << 2) + th;
            if (fi >= cnt) fi = cnt - 1;   // duplicate row: identical result
            rown[th] = flagList[fi];
        }
        __syncthreads();
#pragma unroll
        for (int r = 0; r < 4; ++r) {
            int n = rown[r];
            zsh[r][th] = Z[(size_t)(((n >> 10) << 8) + th) * HWN + (n & 1023)];
        }
        __syncthreads();
        float zr[4][16];
#pragma unroll
        for (int r = 0; r < 4; ++r)
#pragma unroll
            for (int jq = 0; jq < 16; ++jq) zr[r][jq] = zsh[r][(l << 4) + jq];
        float z2v[4];
#pragma unroll
        for (int r = 0; r < 4; ++r) z2v[r] = z2[rown[r]];
        float gbest[4];
        int bi[4];
#pragma unroll
        for (int r = 0; r < 4; ++r) { gbest[r] = __builtin_inff(); bi[r] = 0; }

        const int base = q << 8;
        for (int it = 0; it < 4; ++it) {
#pragma unroll
            for (int u = 0; u < 4; ++u) {      // ascending code order
                const int c = base + (it << 6) + (u << 4) + g;
                const float* er = &E[(size_t)c * DD + (l << 4)];
                float4 a0 = *reinterpret_cast<const float4*>(er);
                float4 a1 = *reinterpret_cast<const float4*>(er + 4);
                float4 a2 = *reinterpret_cast<const float4*>(er + 8);
                float4 a3 = *reinterpret_cast<const float4*>(er + 12);
                double dots[4];
#pragma unroll
                for (int r = 0; r < 4; ++r) {
                    double s0 = (double)a0.x * zr[r][0]  + (double)a0.y * zr[r][1]
                              + (double)a0.z * zr[r][2]  + (double)a0.w * zr[r][3];
                    double s1 = (double)a1.x * zr[r][4]  + (double)a1.y * zr[r][5]
                              + (double)a1.z * zr[r][6]  + (double)a1.w * zr[r][7];
                    double s2 = (double)a2.x * zr[r][8]  + (double)a2.y * zr[r][9]
                              + (double)a2.z * zr[r][10] + (double)a2.w * zr[r][11];
                    double s3 = (double)a3.x * zr[r][12] + (double)a3.y * zr[r][13]
                              + (double)a3.z * zr[r][14] + (double)a3.w * zr[r][15];
                    dots[r] = (s0 + s1) + (s2 + s3);
                }
#pragma unroll
                for (int m = 1; m <= 8; m <<= 1) {
#pragma unroll
                    for (int r = 0; r < 4; ++r)
                        dots[r] += __shfl_xor(dots[r], m);
                }
                if (l == 0) {
#pragma unroll
                    for (int r = 0; r < 4; ++r) {
                        float cc = (float)dots[r];
                        float t2 = __fmul_rn(2.0f, cc);
                        float gg = __fsub_rn(__fadd_rn(z2v[r], e2[c]), t2);
                        if (gg < gbest[r]) { gbest[r] = gg; bi[r] = c; }
                    }
                }
            }
        }
        if (l == 0) {
#pragma unroll
            for (int r = 0; r < 4; ++r) { gbv[g][r] = gbest[r]; gbi[g][r] = bi[r]; }
        }
        __syncthreads();
        if (th < 4) {
            const int r = th;
            float best = gbv[0][r]; int bbi = gbi[0][r];
            for (int qq = 1; qq < 16; ++qq) {
                float v = gbv[qq][r]; int vi = gbi[qq][r];
                if (v < best || (v == best && vi < bbi)) { best = v; bbi = vi; }
            }
            u64 pack = ((u64)__float_as_uint(best) << 32) | (unsigned)bbi;
            atomicMin(&bestG[rown[r]], pack);
        }
    }
}

// ---- unpack bestG -> bestIdx for flagged rows ----
__global__ __launch_bounds__(256) void k_final(const int* __restrict__ flagList,
                                               const int* __restrict__ flagCount,
                                               const u64* __restrict__ bestG,
                                               int* __restrict__ bestIdx) {
    const int cnt = *flagCount;
    for (int j = (blockIdx.x << 8) + threadIdx.x; j < cnt; j += (int)(gridDim.x << 8)) {
        int n = flagList[j];
        bestIdx[n] = (int)(unsigned)(bestG[n] & 0xFFFFFFFFull);
    }
}

// ======== fp32 fallback distance pass (used if ws too small) ========
#define UPD(m1, m2, i1, s, k)                            \
    do {                                                 \
        if ((s) < (m1)) { m2 = m1; m1 = (s); i1 = (k); } \
        else if ((s) < (m2)) { m2 = (s); }               \
    } while (0)

#define FMAJ(j, EV, C)                                   \
    acc[0][j] = fmaf(z4.x, EV.C, acc[0][j]);             \
    acc[1][j] = fmaf(z4.y, EV.C, acc[1][j]);             \
    acc[2][j] = fmaf(z4.z, EV.C, acc[2][j]);             \
    acc[3][j] = fmaf(z4.w, EV.C, acc[3][j]);

#define UROUND(u, C)                                                          \
    {                                                                         \
        float4 z4 = *reinterpret_cast<const float4*>(&zs[dq + u][ty4]);       \
        FMAJ(0, e0, C) FMAJ(1, e1, C) FMAJ(2, e2v, C) FMAJ(3, e3, C)          \
        FMAJ(4, e4, C) FMAJ(5, e5, C) FMAJ(6, e6, C) FMAJ(7, e7, C)           \
    }

__global__ __launch_bounds__(256, 3) void k_dist_f32(const float* __restrict__ Z,
                                                     const float* __restrict__ E,
                                                     const float* __restrict__ e2,
                                                     int* __restrict__ bestIdx) {
    __shared__ float zs[64][68];
    __shared__ float es[128][68];
    const int th = threadIdx.x;
    const int n0 = blockIdx.x << 6;
    const int b = n0 >> 10;
    const int hw0 = n0 & 1023;
    const int tx = th & 15;
    const int ty = th >> 4;
    const int ty4 = ty << 2;
    float m1[4], m2[4];
    int idx[4];
#pragma unroll
    for (int i = 0; i < 4; ++i) { m1[i] = __builtin_inff(); m2[i] = __builtin_inff(); idx[i] = 0; }
    for (int ct = 0; ct < 8; ++ct) {
        float acc[4][8];
#pragma unroll
        for (int i = 0; i < 4; ++i)
#pragma unroll
            for (int j = 0; j < 8; ++j) acc[i][j] = 0.f;
        for (int dc = 0; dc < 4; ++dc) {
            __syncthreads();
#pragma unroll
            for (int j = 0; j < 4; ++j) {
                int i4 = (j << 8) + th;
                int dd = i4 >> 4;
                int rr = (i4 & 15) << 2;
                *reinterpret_cast<float4*>(&zs[dd][rr]) =
                    *reinterpret_cast<const float4*>(
                        &Z[(size_t)((b << 8) + (dc << 6) + dd) * HWN + hw0 + rr]);
            }
#pragma unroll
            for (int j = 0; j < 8; ++j) {
                int i4 = (j << 8) + th;
                int c = i4 >> 4;
                int d4 = (i4 & 15) << 2;
                *reinterpret_cast<float4*>(&es[c][d4]) =
                    *reinterpret_cast<const float4*>(
                        &E[(size_t)((ct << 7) + c) * DD + (dc << 6) + d4]);
            }
            __syncthreads();
#pragma unroll
            for (int dq = 0; dq < 64; dq += 4) {
                float4 e0 = *reinterpret_cast<const float4*>(&es[tx][dq]);
                float4 e1 = *reinterpret_cast<const float4*>(&es[tx + 16][dq]);
                float4 e2v = *reinterpret_cast<const float4*>(&es[tx + 32][dq]);
                float4 e3 = *reinterpret_cast<const float4*>(&es[tx + 48][dq]);
                float4 e4 = *reinterpret_cast<const float4*>(&es[tx + 64][dq]);
                float4 e5 = *reinterpret_cast<const float4*>(&es[tx + 80][dq]);
                float4 e6 = *reinterpret_cast<const float4*>(&es[tx + 96][dq]);
                float4 e7 = *reinterpret_cast<const float4*>(&es[tx + 112][dq]);
                UROUND(0, x)
                UROUND(1, y)
                UROUND(2, z)
                UROUND(3, w)
            }
        }
#pragma unroll
        for (int j = 0; j < 8; ++j) {
            int c = (ct << 7) + tx + (j << 4);
            float en = e2[c];
#pragma unroll
            for (int i = 0; i < 4; ++i) {
                float s = fmaf(-2.f, acc[i][j], en);
                UPD(m1[i], m2[i], idx[i], s, c);
            }
        }
    }
    __syncthreads();
    float* red = &es[0][0];
#pragma unroll
    for (int i = 0; i < 4; ++i) {
        int r = ty4 + i;
        int base = ((r << 4) + tx) * 3;
        red[base] = m1[i]; red[base + 1] = m2[i]; red[base + 2] = (float)idx[i];
    }
    __syncthreads();
    if (th < 64) {
        float M1 = __builtin_inff(), M2 = __builtin_inff(), I = 3.4e38f;
        for (int t = 0; t < 16; ++t) {
            int base = ((th << 4) + t) * 3;
            float v1 = red[base], v2 = red[base + 1], vi = red[base + 2];
            if (v1 < M1)       { M2 = fminf(M1, v2); M1 = v1; I = vi; }
            else if (v1 == M1) { I = fminf(I, vi); M2 = fminf(M2, v1); M2 = fminf(M2, v2); }
            else               { M2 = fminf(M2, v1); }
        }
        int id = (int)I;
        bestIdx[n0 + th] = (M2 - M1 < MARGIN) ? (id | FLAGBIT) : id;
    }
}

// -------- fallback-path refine (FLAGBIT scan, unchanged semantics) --------
__global__ __launch_bounds__(64) void k_refine(const float* __restrict__ Z,
                                               const float* __restrict__ E,
                                               const float* __restrict__ e2,
                                               const float* __restrict__ z2,
                                               int* __restrict__ bestIdx) {
    __shared__ float zr[DD];
    const int l = threadIdx.x;
    for (int i = 0; i < 16; ++i) {
        int n = (blockIdx.x << 4) + i;
        if (!(bestIdx[n] & FLAGBIT)) continue;
        int b = n >> 10, hw = n & 1023;
        __syncthreads();
#pragma unroll
        for (int j = 0; j < 4; ++j)
            zr[(l << 2) + j] = Z[(size_t)((b << 8) + (l << 2) + j) * HWN + hw];
        __syncthreads();
        const float z2v = z2[n];
        float gbest = __builtin_inff();
        int bi = KK;
        for (int kk = 0; kk < 16; ++kk) {
            int k = (kk << 6) + l;
            double dot = 0.0;
            for (int d = 0; d < DD; d += 4) {
                float4 e4 = *reinterpret_cast<const float4*>(&E[(size_t)k * DD + d]);
                dot += (double)e4.x * zr[d]     + (double)e4.y * zr[d + 1]
                     + (double)e4.z * zr[d + 2] + (double)e4.w * zr[d + 3];
            }
            float c = (float)dot;
            float t = __fmul_rn(2.0f, c);
            float gg = __fsub_rn(__fadd_rn(z2v, e2[k]), t);
            if (gg < gbest) { gbest = gg; bi = k; }
        }
#pragma unroll
        for (int off = 32; off > 0; off >>= 1) {
            float og = __shfl_down(gbest, off);
            int oi = __shfl_down(bi, off);
            if (og < gbest || (og == gbest && oi < bi)) { gbest = og; bi = oi; }
        }
        if (l == 0) bestIdx[n] = bi;
    }
}

// -------- outputs (MFMA path): idx, loss from Zh, z_q via LDS-staged E --------
__global__ __launch_bounds__(256) void k_out(const ushort* __restrict__ Zh,
                                             const float* __restrict__ E,
                                             const int* __restrict__ bestIdx,
                                             float* __restrict__ out) {
    __shared__ int idxs[64];
    __shared__ float es[64][68];       // 17408 B staged E chunk
    const int th = threadIdx.x;
    const int n0 = blockIdx.x << 6;    // 512 blocks, 64 rows each
    const int b = n0 >> 10;
    const int hw0 = n0 & 1023;

    if (th < 64) {
        int id = bestIdx[n0 + th] & 1023;
        idxs[th] = id;
        out[IDX_OFF + n0 + th] = (float)id;
    }
    __syncthreads();

    // loss (NHWC): lane-adjacent float4 writes; z from Zh (f16, err << threshold)
#pragma unroll
    for (int j = 0; j < 16; ++j) {
        int i4 = (j << 8) + th;        // 0..4095
        int r = i4 >> 6;               // 0..63
        int f = (i4 & 63) << 2;        // 0..252
        int n = n0 + r;
        float4 e4 = *reinterpret_cast<const float4*>(&E[(size_t)idxs[r] * DD + f]);
        ushort4 zu = *reinterpret_cast<const ushort4*>(&Zh[(size_t)n * DD + f]);
        float4 o;
        float t;
        t = e4.x - h2f(zu.x); o.x = t * t;
        t = e4.y - h2f(zu.y); o.y = t * t;
        t = e4.z - h2f(zu.z); o.z = t * t;
        t = e4.w - h2f(zu.w); o.w = t * t;
        *reinterpret_cast<float4*>(&out[LOSS_OFF + (size_t)n * DD + f]) = o;
    }

    // z_q (NCHW): stage gathered E rows per dc-chunk with row-contiguous float4
    // reads, then write hw-coalesced from LDS
    for (int dc = 0; dc < 4; ++dc) {
        __syncthreads();               // protect es from previous dc's reads
        {
            const int r = th >> 2, qd = (th & 3) << 4;
            const float* er = &E[(size_t)idxs[r] * DD + (dc << 6) + qd];
#pragma unroll
            for (int v = 0; v < 4; ++v)
                *reinterpret_cast<float4*>(&es[r][qd + (v << 2)]) =
                    *reinterpret_cast<const float4*>(er + (v << 2));
        }
        __syncthreads();
#pragma unroll
        for (int j = 0; j < 16; ++j) {
            int li = (j << 8) + th;
            int dd = li >> 6;
            int r = li & 63;
            out[ZQ_OFF + (size_t)((b << 8) + (dc << 6) + dd) * HWN + hw0 + r] =
                es[r][dd];
        }
    }
}

// -------- outputs (fallback path): reads Z --------
__global__ __launch_bounds__(256) void k_out_f32(const float* __restrict__ Z,
                                                 const float* __restrict__ E,
                                                 const int* __restrict__ bestIdx,
                                                 float* __restrict__ out) {
    __shared__ float zc[64][68];
    __shared__ int idxs[64];
    const int th = threadIdx.x;
    const int n0 = blockIdx.x << 6;
    const int b = n0 >> 10;
    const int hw0 = n0 & 1023;

    if (th < 64) {
        int id = bestIdx[n0 + th] & 1023;
        idxs[th] = id;
        out[IDX_OFF + n0 + th] = (float)id;
    }
    __syncthreads();

    for (int dc = 0; dc < 4; ++dc) {
        __syncthreads();
#pragma unroll
        for (int j = 0; j < 16; ++j) {
            int li = (j << 8) + th;
            int dd = li >> 6;
            int r = li & 63;
            zc[r][dd] = Z[(size_t)((b << 8) + (dc << 6) + dd) * HWN + hw0 + r];
        }
        __syncthreads();
#pragma unroll
        for (int j = 0; j < 4; ++j) {
            int i4 = (j << 8) + th;
            int r = i4 >> 4;
            int f = (i4 & 15) << 2;
            float4 e4 = *reinterpret_cast<const float4*>(
                &E[(size_t)idxs[r] * DD + (dc << 6) + f]);
            float4 z4 = *reinterpret_cast<const float4*>(&zc[r][f]);
            float4 o;
            o.x = (e4.x - z4.x) * (e4.x - z4.x);
            o.y = (e4.y - z4.y) * (e4.y - z4.y);
            o.z = (e4.z - z4.z) * (e4.z - z4.z);
            o.w = (e4.w - z4.w) * (e4.w - z4.w);
            *reinterpret_cast<float4*>(
                &out[LOSS_OFF + (size_t)(n0 + r) * DD + (dc << 6) + f]) = o;
        }
#pragma unroll
        for (int j = 0; j < 16; ++j) {
            int li = (j << 8) + th;
            int dd = li >> 6;
            int r = li & 63;
            out[ZQ_OFF + (size_t)((b << 8) + (dc << 6) + dd) * HWN + hw0 + r] =
                E[(size_t)idxs[r] * DD + (dc << 6) + dd];
        }
    }
}

extern "C" void kernel_launch(void* const* d_in, const int* in_sizes, int n_in,
                              void* d_out, int out_size, void* d_ws, size_t ws_size,
                              hipStream_t stream) {
    const float* Z = (const float*)d_in[0];           // [32,256,32,32] f32
    const float* E = (const float*)d_in[1];           // [1024,256] f32
    float* out = (float*)d_out;
    char* ws = (char*)d_ws;
    float* e2 = (float*)ws;
    float* z2 = (float*)(ws + 4096);
    int* bestIdx = (int*)(ws + 135168);

    k_e2<<<32, 256, 0, stream>>>(E, e2);

    if (ws_size >= WS_NEED) {
        float* part = (float*)(ws + 266240);
        ushort* Eh = (ushort*)(ws + 3411968);
        ushort* Zh = (ushort*)(ws + 4460544);
        u64* bestG = (u64*)(ws + 21237760);
        int* flagCount = (int*)(ws + 38014976);
        int* flagList = (int*)(ws + 38015040);
        k_prepE<<<256, 256, 0, stream>>>(E, Eh, flagCount);
        k_prepZ2<<<1024, 256, 0, stream>>>(Z, Zh, z2);
        k_dist_mfma<<<2048, 256, 0, stream>>>(Zh, Eh, e2, part);
        k_combine<<<NN / 256, 256, 0, stream>>>(part, bestIdx, flagList, flagCount, bestG);
        k_refine5<<<2048, 256, 0, stream>>>(Z, E, e2, z2, flagList, flagCount, bestG);
        k_final<<<64, 256, 0, stream>>>(flagList, flagCount, bestG, bestIdx);
        k_out<<<NN / 64, 256, 0, stream>>>(Zh, E, bestIdx, out);
    } else {
        k_z2<<<NN / 256, 256, 0, stream>>>(Z, z2);
        k_dist_f32<<<NN / 64, 256, 0, stream>>>(Z, E, e2, bestIdx);
        k_refine<<<NN / 16, 64, 0, stream>>>(Z, E, e2, z2, bestIdx);
        k_out_f32<<<NN / 64, 256, 0, stream>>>(Z, E, bestIdx, out);
    }
}

// Round 28
// 133.073 us; speedup vs baseline: 1.2273x; 1.0325x over previous
//
#include <hip/hip_runtime.h>

#define DD 256
#define HWN 1024
#define NN 32768
#define KK 1024
#define MARGIN 1e-4f
#define FLAGBIT (1 << 30)

// f32-element offsets into d_out (out_size = 16809984 floats):
#define ZQ_OFF   0          // z_q   [32,256,32,32]
#define IDX_OFF  8388608    // idx   [32768]
#define LOSS_OFF 8421376    // loss  [32,32,32,256] (NHWC)

// ws layout (MFMA path needs WS_NEED bytes; else fp32 fallback):
// [0, 4096)            float e2[1024]
// [4096, 135168)       float z2[32768]
// [135168, 266240)     int   bestIdx[32768]  (FLAGBIT marks near-tie rows)
// [266240, 3411968)    float part[32768][8][3]
// [3411968, 3936256)   ushort Eh[1024][256]   (f16 of 1024*E)
// [4460544, 21237760)  ushort Zh[32768][256]  (f16 of Z, [n][d])
// [21237760, 21499904) ull bestG[32768]       (packed g|idx atomicMin merge)
// [38014976, 38015040) int flagCount
// [38015040, 38146112) int flagList[32768]
#define WS_NEED 38146112

typedef __attribute__((ext_vector_type(8))) _Float16 f16x8;
typedef __attribute__((ext_vector_type(4))) float f32x4;
typedef unsigned long long u64;

__device__ __forceinline__ ushort f2h(float x) {
    _Float16 h = (_Float16)x;                  // RNE
    return *reinterpret_cast<ushort*>(&h);
}
__device__ __forceinline__ float h2f(ushort u) {
    _Float16 h = *reinterpret_cast<_Float16*>(&u);
    return (float)h;
}

// LDS slot16 index for element (row r, k-group kgi) — bank-spread swizzle.
__device__ __forceinline__ int swz(int r, int kgi) {
    return (r << 2) + (kgi ^ (r & 3) ^ ((r >> 2) & 3));
}

// -- fused: E -> Eh (f16 1024*E) + numpy-exact e2 + flagCount zero --
__global__ __launch_bounds__(256) void k_prepEf(const float* __restrict__ E,
                                                ushort* __restrict__ Eh,
                                                float* __restrict__ e2,
                                                int* __restrict__ flagCount) {
    __shared__ float ec[32][257];      // 32 E rows
    const int g = blockIdx.x;          // 32 blocks x 32 rows
    const int th = threadIdx.x;
    const int r0 = g << 5;
    if (g == 0 && th == 0) *flagCount = 0;
#pragma unroll
    for (int j = 0; j < 32; ++j)
        ec[j][th] = E[(size_t)r0 * DD + (j << 8) + th];
    __syncthreads();

    // Eh: f16(1024*E), 64B/thread contiguous
    {
        const int r = th >> 3, c = th & 7;
        ushort hs[32];
#pragma unroll
        for (int i = 0; i < 32; ++i)
            hs[i] = f2h(__fmul_rn(ec[r][(c << 5) + i], 1024.f));
        size_t addr = (size_t)(r0 + r) * DD + (c << 5);
#pragma unroll
        for (int q = 0; q < 4; ++q)
            *reinterpret_cast<f16x8*>(&Eh[addr + (q << 3)]) =
                *reinterpret_cast<f16x8*>(&hs[q << 3]);
    }

    // e2: numpy pairwise, parallel (validated bit-exact structure)
    {
        const int row = th >> 3, j = th & 7;
        const float* a = &ec[row][0];
        float x0 = a[j];
        float rr0 = __fmul_rn(x0, x0);
        float x1 = a[128 + j];
        float rr1 = __fmul_rn(x1, x1);
#pragma unroll
        for (int i = 8; i < 128; i += 8) {
            float y0 = a[i + j];
            rr0 = __fadd_rn(rr0, __fmul_rn(y0, y0));
            float y1 = a[128 + i + j];
            rr1 = __fadd_rn(rr1, __fmul_rn(y1, y1));
        }
#pragma unroll
        for (int m = 1; m <= 4; m <<= 1) {
            rr0 = __fadd_rn(rr0, __shfl_xor(rr0, m));
            rr1 = __fadd_rn(rr1, __shfl_xor(rr1, m));
        }
        if (j == 0) e2[r0 + row] = __fadd_rn(rr0, rr1);
    }
}

// -- e2 standalone (fallback path only) --
__global__ __launch_bounds__(256) void k_e2(const float* __restrict__ E,
                                            float* __restrict__ e2) {
    const int th = threadIdx.x;
    const int row = (blockIdx.x << 5) + (th >> 3);
    const int j = th & 7;
    const float* a = E + (size_t)row * DD;
    float x0 = a[j];
    float r0 = __fmul_rn(x0, x0);
    float x1 = a[128 + j];
    float r1 = __fmul_rn(x1, x1);
#pragma unroll
    for (int i = 8; i < 128; i += 8) {
        float y0 = a[i + j];
        r0 = __fadd_rn(r0, __fmul_rn(y0, y0));
        float y1 = a[128 + i + j];
        r1 = __fadd_rn(r1, __fmul_rn(y1, y1));
    }
#pragma unroll
    for (int m = 1; m <= 4; m <<= 1) {
        r0 = __fadd_rn(r0, __shfl_xor(r0, m));
        r1 = __fadd_rn(r1, __shfl_xor(r1, m));
    }
    if (j == 0) e2[row] = __fadd_rn(r0, r1);
}

// -- fused: Z transpose (32-row tiles, 128B segments) -> Zh f16 + parallel z2 --
__global__ __launch_bounds__(256) void k_prepZ2(const float* __restrict__ Z,
                                                ushort* __restrict__ Zh,
                                                float* __restrict__ z2) {
    __shared__ float zc[32][257];      // 32896 B
    const int g = blockIdx.x;          // 1024 blocks: 32 rows each
    const int b = g >> 5;
    const int hw0 = (g & 31) << 5;
    const int th = threadIdx.x;
    const int n0 = (b << 10) + hw0;

#pragma unroll
    for (int j = 0; j < 32; ++j) {
        int li = (j << 8) + th;        // 0..8191
        int d = li >> 5;
        int hl = li & 31;              // 32 consecutive hw = 128B segment
        zc[hl][d] = Z[(size_t)((b << 8) + d) * HWN + hw0 + hl];
    }
    __syncthreads();

    // f16 (RNE), [n][d] layout, 64B/thread contiguous
    {
        int r = th >> 3, c = th & 7;
        ushort hs[32];
#pragma unroll
        for (int i = 0; i < 32; ++i) hs[i] = f2h(zc[r][(c << 5) + i]);
        size_t addr = (size_t)(n0 + r) * DD + (c << 5);
#pragma unroll
        for (int q = 0; q < 4; ++q)
            *reinterpret_cast<f16x8*>(&Zh[addr + (q << 3)]) =
                *reinterpret_cast<f16x8*>(&hs[q << 3]);
    }

    // z2: numpy pairwise, parallel (validated bit-exact structure)
    {
        const int row = th >> 3, j = th & 7;
        const float* a = &zc[row][0];
        float x0 = a[j];
        float r0 = __fmul_rn(x0, x0);
        float x1 = a[128 + j];
        float r1 = __fmul_rn(x1, x1);
#pragma unroll
        for (int i = 8; i < 128; i += 8) {
            float y0 = a[i + j];
            r0 = __fadd_rn(r0, __fmul_rn(y0, y0));
            float y1 = a[128 + i + j];
            r1 = __fadd_rn(r1, __fmul_rn(y1, y1));
        }
#pragma unroll
        for (int m = 1; m <= 4; m <<= 1) {
            r0 = __fadd_rn(r0, __shfl_xor(r0, m));
            r1 = __fadd_rn(r1, __shfl_xor(r1, m));
        }
        if (j == 0) z2[n0 + row] = __fadd_rn(r0, r1);
    }
}

// ---------------- z2 standalone (fallback path only) ----------------
__global__ __launch_bounds__(256) void k_z2(const float* __restrict__ Z,
                                            float* __restrict__ z2) {
    int n = (blockIdx.x << 8) + threadIdx.x;
    int b = n >> 10, hw = n & 1023;
    const float* base = Z + (size_t)(b << 8) * HWN + hw;
    float half_[2];
#pragma unroll
    for (int h = 0; h < 2; ++h) {
        const float* a = base + (size_t)(h << 7) * HWN;
        float r[8];
#pragma unroll
        for (int j = 0; j < 8; ++j) {
            float x = a[(size_t)j * HWN];
            r[j] = __fmul_rn(x, x);
        }
        for (int i = 8; i < 128; i += 8) {
#pragma unroll
            for (int j = 0; j < 8; ++j) {
                float x = a[(size_t)(i + j) * HWN];
                r[j] = __fadd_rn(r[j], __fmul_rn(x, x));
            }
        }
        half_[h] = __fadd_rn(__fadd_rn(__fadd_rn(r[0], r[1]), __fadd_rn(r[2], r[3])),
                             __fadd_rn(__fadd_rn(r[4], r[5]), __fadd_rn(r[6], r[7])));
    }
    z2[n] = __fadd_rn(half_[0], half_[1]);
}

// --- MFMA distance pass: r16 structure, LDS-reuse epilogue -> 5 blocks/CU ---
__device__ __forceinline__ void stage_kc(const ushort* __restrict__ Zh,
                                         const ushort* __restrict__ Eh,
                                         ushort* ldsbuf, int n0, int c0, int kc,
                                         int wid, int lane) {
#pragma unroll
    for (int is = 0; is < 4; ++is) {
        const int chunk = (wid << 2) + is;   // 0..15 (wave-uniform)
        const int arr = chunk >> 3;          // 0: zh, 1: eh
        const int cb8 = chunk & 7;           // chunk within array
        const int s = (cb8 << 6) + lane;     // slot16 this lane fills
        const int r = s >> 2;
        const int kgi = (s & 3) ^ (r & 3) ^ ((r >> 2) & 3);   // inverse swizzle
        const ushort* g = (arr == 0) ? Zh + (size_t)(n0 + r) * DD
                                     : Eh + (size_t)(c0 + r) * DD;
        g += (kc << 5) + (kgi << 3);
        ushort* l = ldsbuf + arr * 4096 + (cb8 << 9);
        __builtin_amdgcn_global_load_lds(
            (const __attribute__((address_space(1))) void*)g,
            (__attribute__((address_space(3))) void*)l, 16, 0, 0);
    }
}

__global__ __launch_bounds__(256) void k_dist_mfma(const ushort* __restrict__ Zh,
                                                   const ushort* __restrict__ Eh,
                                                   const float* __restrict__ e2,
                                                   float* __restrict__ part) {
    __shared__ ushort lds[2][2][4096];     // 32768 B total -> 5 blocks/CU
    float (*red)[2][3] = reinterpret_cast<float (*)[2][3]>(&lds[0][0][0]);

    const int B = blockIdx.x;              // 2048 blocks
    const int xcd = B & 7;
    const int j = B >> 3;                  // 0..255
    const int cb = j & 7;
    const int rb = (xcd << 5) + (j >> 3);
    const int n0 = rb << 7, c0 = cb << 7;
    const int th = threadIdx.x;
    const int wid = th >> 6, lane = th & 63;
    const int wr = wid >> 1, wc = wid & 1;
    const int fr = lane & 15, kgi = lane >> 4;

    f32x4 acc[4][4];
#pragma unroll
    for (int i = 0; i < 4; ++i)
#pragma unroll
        for (int jj = 0; jj < 4; ++jj) acc[i][jj] = (f32x4){0.f, 0.f, 0.f, 0.f};

    int zoff[4], eoff[4];
#pragma unroll
    for (int mi = 0; mi < 4; ++mi)
        zoff[mi] = swz((wr << 6) + (mi << 4) + fr, kgi) << 4;
#pragma unroll
    for (int ni = 0; ni < 4; ++ni)
        eoff[ni] = swz((wc << 6) + (ni << 4) + fr, kgi) << 4;

    stage_kc(Zh, Eh, &lds[0][0][0], n0, c0, 0, wid, lane);

    for (int kc = 0; kc < 8; ++kc) {
        __builtin_amdgcn_s_barrier();
        if (kc < 7) {
            stage_kc(Zh, Eh, &lds[(kc + 1) & 1][0][0], n0, c0, kc + 1, wid, lane);
            asm volatile("s_waitcnt vmcnt(4)" ::: "memory");
        } else {
            asm volatile("s_waitcnt vmcnt(0)" ::: "memory");
        }
        __builtin_amdgcn_s_barrier();

        const char* zb  = (const char*)&lds[kc & 1][0][0];
        const char* ebh = (const char*)&lds[kc & 1][1][0];
        f16x8 za[4], ea[4];
#pragma unroll
        for (int mi = 0; mi < 4; ++mi)
            za[mi] = *reinterpret_cast<const f16x8*>(zb + zoff[mi]);
#pragma unroll
        for (int ni = 0; ni < 4; ++ni)
            ea[ni] = *reinterpret_cast<const f16x8*>(ebh + eoff[ni]);
        __builtin_amdgcn_s_setprio(1);
#pragma unroll
        for (int mi = 0; mi < 4; ++mi)
#pragma unroll
            for (int ni = 0; ni < 4; ++ni)
                acc[mi][ni] = __builtin_amdgcn_mfma_f32_16x16x32_f16(za[mi], ea[ni], acc[mi][ni], 0, 0, 0);
        __builtin_amdgcn_s_setprio(0);
    }

    __syncthreads();   // all frag LDS reads consumed -> safe to reuse lds as red

    float e2v[4];
#pragma unroll
    for (int ni = 0; ni < 4; ++ni) e2v[ni] = e2[c0 + (wc << 6) + (ni << 4) + fr];

#pragma unroll
    for (int mi = 0; mi < 4; ++mi) {
#pragma unroll
        for (int jj = 0; jj < 4; ++jj) {
            float m1 = __builtin_inff(), m2 = __builtin_inff(), bi = 3.4e38f;
#pragma unroll
            for (int ni = 0; ni < 4; ++ni) {
                float s = fmaf(-0x1p-9f, acc[mi][ni][jj], e2v[ni]);  // -2*dot, undo x1024
                float c = (float)(c0 + (wc << 6) + (ni << 4) + fr);
                if (s < m1)      { m2 = m1; m1 = s; bi = c; }
                else if (s < m2) { m2 = s; }
            }
#pragma unroll
            for (int m = 1; m <= 8; m <<= 1) {
                float om1 = __shfl_xor(m1, m);
                float om2 = __shfl_xor(m2, m);
                float obi = __shfl_xor(bi, m);
                if (om1 < m1)       { m2 = fminf(m1, om2); m1 = om1; bi = obi; }
                else if (om1 == m1) { bi = fminf(bi, obi); m2 = m1; }
                else                { m2 = fminf(m2, om1); }
            }
            if (fr == 0) {
                int row = (wr << 6) + (mi << 4) + (kgi << 2) + jj;
                red[row][wc][0] = m1; red[row][wc][1] = m2; red[row][wc][2] = bi;
            }
        }
    }
    __syncthreads();
    if (th < 128) {
        float M1 = red[th][0][0], M2 = red[th][0][1], I = red[th][0][2];
        float v1 = red[th][1][0], v2 = red[th][1][1], vi = red[th][1][2];
        if (v1 < M1)       { M2 = fminf(M1, v2); M1 = v1; I = vi; }
        else if (v1 == M1) { I = fminf(I, vi); M2 = M1; }
        else               { M2 = fminf(M2, v1); }
        size_t p = ((size_t)(n0 + th) * 8 + cb) * 3;
        part[p] = M1; part[p + 1] = M2; part[p + 2] = I;
    }
}

// -- combine -> bestIdx (FLAGBIT near-tie) + flag list + bestG init --
// (FLAGBIT+bestG scheme validated in r25/r26 passing runs)
__global__ __launch_bounds__(256) void k_combine(const float* __restrict__ part,
                                                 int* __restrict__ bestIdx,
                                                 int* __restrict__ flagList,
                                                 int* __restrict__ flagCount,
                                                 u64* __restrict__ bestG) {
    int n = (blockIdx.x << 8) + threadIdx.x;
    const float* p = part + (size_t)n * 24;
    float M1 = __builtin_inff(), M2 = __builtin_inff(), I = 3.4e38f;
    for (int c = 0; c < 8; ++c) {
        float v1 = p[c * 3], v2 = p[c * 3 + 1], vi = p[c * 3 + 2];
        if (v1 < M1)       { M2 = fminf(M1, v2); M1 = v1; I = vi; }
        else if (v1 == M1) { I = fminf(I, vi); M2 = M1; }
        else               { M2 = fminf(M2, v1); }
    }
    if (M2 - M1 < MARGIN) {
        bestIdx[n] = (int)I | FLAGBIT;
        bestG[n] = ~0ull;
        int pos = atomicAdd(flagCount, 1);
        flagList[pos] = n;
    } else {
        bestIdx[n] = (int)I;
    }
}

// ---- np-f32-grid re-argmin: item = (4-row group, code quarter); each E
// ---- float4 feeds 4 dot-chains; merge via u64 atomicMin (g>0 always).
__global__ __launch_bounds__(256) void k_refine5(const float* __restrict__ Z,
                                                 const float* __restrict__ E,
                                                 const float* __restrict__ e2,
                                                 const float* __restrict__ z2,
                                                 const int* __restrict__ flagList,
                                                 const int* __restrict__ flagCount,
                                                 u64* __restrict__ bestG) {
    __shared__ float zsh[4][DD];
    __shared__ float gbv[16][4];
    __shared__ int gbi[16][4];
    __shared__ int rown[4];
    const int th = threadIdx.x;
    const int g = th >> 4;             // code group 0..15
    const int l = th & 15;             // lane in group
    const int cnt = *flagCount;
    const int items = ((cnt + 3) >> 2) << 2;   // 4 quarters per 4-row group

    for (int jj = blockIdx.x; jj < items; jj += (int)gridDim.x) {
        const int gi = jj >> 2;        // row group
        const int q = jj & 3;          // code quarter
        __syncthreads();               // protect shared state from prev item
        if (th < 4) {
            int fi = (gi << 2) + th;
            if (fi >= cnt) fi = cnt - 1;   // duplicate row: identical result
            rown[th] = flagList[fi];
        }
        __syncthreads();
#pragma unroll
        for (int r = 0; r < 4; ++r) {
            int n = rown[r];
            zsh[r][th] = Z[(size_t)(((n >> 10) << 8) + th) * HWN + (n & 1023)];
        }
        __syncthreads();
        float zr[4][16];
#pragma unroll
        for (int r = 0; r < 4; ++r)
#pragma unroll
            for (int jq = 0; jq < 16; ++jq) zr[r][jq] = zsh[r][(l << 4) + jq];
        float z2v[4];
#pragma unroll
        for (int r = 0; r < 4; ++r) z2v[r] = z2[rown[r]];
        float gbest[4];
        int bi[4];
#pragma unroll
        for (int r = 0; r < 4; ++r) { gbest[r] = __builtin_inff(); bi[r] = 0; }

        const int base = q << 8;
        for (int it = 0; it < 4; ++it) {
#pragma unroll
            for (int u = 0; u < 4; ++u) {      // ascending code order
                const int c = base + (it << 6) + (u << 4) + g;
                const float* er = &E[(size_t)c * DD + (l << 4)];
                float4 a0 = *reinterpret_cast<const float4*>(er);
                float4 a1 = *reinterpret_cast<const float4*>(er + 4);
                float4 a2 = *reinterpret_cast<const float4*>(er + 8);
                float4 a3 = *reinterpret_cast<const float4*>(er + 12);
                double dots[4];
#pragma unroll
                for (int r = 0; r < 4; ++r) {
                    double s0 = (double)a0.x * zr[r][0]  + (double)a0.y * zr[r][1]
                              + (double)a0.z * zr[r][2]  + (double)a0.w * zr[r][3];
                    double s1 = (double)a1.x * zr[r][4]  + (double)a1.y * zr[r][5]
                              + (double)a1.z * zr[r][6]  + (double)a1.w * zr[r][7];
                    double s2 = (double)a2.x * zr[r][8]  + (double)a2.y * zr[r][9]
                              + (double)a2.z * zr[r][10] + (double)a2.w * zr[r][11];
                    double s3 = (double)a3.x * zr[r][12] + (double)a3.y * zr[r][13]
                              + (double)a3.z * zr[r][14] + (double)a3.w * zr[r][15];
                    dots[r] = (s0 + s1) + (s2 + s3);
                }
#pragma unroll
                for (int m = 1; m <= 8; m <<= 1) {
#pragma unroll
                    for (int r = 0; r < 4; ++r)
                        dots[r] += __shfl_xor(dots[r], m);
                }
                if (l == 0) {
#pragma unroll
                    for (int r = 0; r < 4; ++r) {
                        float cc = (float)dots[r];
                        float t2 = __fmul_rn(2.0f, cc);
                        float gg = __fsub_rn(__fadd_rn(z2v[r], e2[c]), t2);
                        if (gg < gbest[r]) { gbest[r] = gg; bi[r] = c; }
                    }
                }
            }
        }
        if (l == 0) {
#pragma unroll
            for (int r = 0; r < 4; ++r) { gbv[g][r] = gbest[r]; gbi[g][r] = bi[r]; }
        }
        __syncthreads();
        if (th < 4) {
            const int r = th;
            float best = gbv[0][r]; int bbi = gbi[0][r];
            for (int qq = 1; qq < 16; ++qq) {
                float v = gbv[qq][r]; int vi = gbi[qq][r];
                if (v < best || (v == best && vi < bbi)) { best = v; bbi = vi; }
            }
            u64 pack = ((u64)__float_as_uint(best) << 32) | (unsigned)bbi;
            atomicMin(&bestG[rown[r]], pack);
        }
    }
}

// ======== fp32 fallback distance pass (used if ws too small) ========
#define UPD(m1, m2, i1, s, k)                            \
    do {                                                 \
        if ((s) < (m1)) { m2 = m1; m1 = (s); i1 = (k); } \
        else if ((s) < (m2)) { m2 = (s); }               \
    } while (0)

#define FMAJ(j, EV, C)                                   \
    acc[0][j] = fmaf(z4.x, EV.C, acc[0][j]);             \
    acc[1][j] = fmaf(z4.y, EV.C, acc[1][j]);             \
    acc[2][j] = fmaf(z4.z, EV.C, acc[2][j]);             \
    acc[3][j] = fmaf(z4.w, EV.C, acc[3][j]);

#define UROUND(u, C)                                                          \
    {                                                                         \
        float4 z4 = *reinterpret_cast<const float4*>(&zs[dq + u][ty4]);       \
        FMAJ(0, e0, C) FMAJ(1, e1, C) FMAJ(2, e2v, C) FMAJ(3, e3, C)          \
        FMAJ(4, e4, C) FMAJ(5, e5, C) FMAJ(6, e6, C) FMAJ(7, e7, C)           \
    }

__global__ __launch_bounds__(256, 3) void k_dist_f32(const float* __restrict__ Z,
                                                     const float* __restrict__ E,
                                                     const float* __restrict__ e2,
                                                     int* __restrict__ bestIdx) {
    __shared__ float zs[64][68];
    __shared__ float es[128][68];
    const int th = threadIdx.x;
    const int n0 = blockIdx.x << 6;
    const int b = n0 >> 10;
    const int hw0 = n0 & 1023;
    const int tx = th & 15;
    const int ty = th >> 4;
    const int ty4 = ty << 2;
    float m1[4], m2[4];
    int idx[4];
#pragma unroll
    for (int i = 0; i < 4; ++i) { m1[i] = __builtin_inff(); m2[i] = __builtin_inff(); idx[i] = 0; }
    for (int ct = 0; ct < 8; ++ct) {
        float acc[4][8];
#pragma unroll
        for (int i = 0; i < 4; ++i)
#pragma unroll
            for (int j = 0; j < 8; ++j) acc[i][j] = 0.f;
        for (int dc = 0; dc < 4; ++dc) {
            __syncthreads();
#pragma unroll
            for (int j = 0; j < 4; ++j) {
                int i4 = (j << 8) + th;
                int dd = i4 >> 4;
                int rr = (i4 & 15) << 2;
                *reinterpret_cast<float4*>(&zs[dd][rr]) =
                    *reinterpret_cast<const float4*>(
                        &Z[(size_t)((b << 8) + (dc << 6) + dd) * HWN + hw0 + rr]);
            }
#pragma unroll
            for (int j = 0; j < 8; ++j) {
                int i4 = (j << 8) + th;
                int c = i4 >> 4;
                int d4 = (i4 & 15) << 2;
                *reinterpret_cast<float4*>(&es[c][d4]) =
                    *reinterpret_cast<const float4*>(
                        &E[(size_t)((ct << 7) + c) * DD + (dc << 6) + d4]);
            }
            __syncthreads();
#pragma unroll
            for (int dq = 0; dq < 64; dq += 4) {
                float4 e0 = *reinterpret_cast<const float4*>(&es[tx][dq]);
                float4 e1 = *reinterpret_cast<const float4*>(&es[tx + 16][dq]);
                float4 e2v = *reinterpret_cast<const float4*>(&es[tx + 32][dq]);
                float4 e3 = *reinterpret_cast<const float4*>(&es[tx + 48][dq]);
                float4 e4 = *reinterpret_cast<const float4*>(&es[tx + 64][dq]);
                float4 e5 = *reinterpret_cast<const float4*>(&es[tx + 80][dq]);
                float4 e6 = *reinterpret_cast<const float4*>(&es[tx + 96][dq]);
                float4 e7 = *reinterpret_cast<const float4*>(&es[tx + 112][dq]);
                UROUND(0, x)
                UROUND(1, y)
                UROUND(2, z)
                UROUND(3, w)
            }
        }
#pragma unroll
        for (int j = 0; j < 8; ++j) {
            int c = (ct << 7) + tx + (j << 4);
            float en = e2[c];
#pragma unroll
            for (int i = 0; i < 4; ++i) {
                float s = fmaf(-2.f, acc[i][j], en);
                UPD(m1[i], m2[i], idx[i], s, c);
            }
        }
    }
    __syncthreads();
    float* red = &es[0][0];
#pragma unroll
    for (int i = 0; i < 4; ++i) {
        int r = ty4 + i;
        int base = ((r << 4) + tx) * 3;
        red[base] = m1[i]; red[base + 1] = m2[i]; red[base + 2] = (float)idx[i];
    }
    __syncthreads();
    if (th < 64) {
        float M1 = __builtin_inff(), M2 = __builtin_inff(), I = 3.4e38f;
        for (int t = 0; t < 16; ++t) {
            int base = ((th << 4) + t) * 3;
            float v1 = red[base], v2 = red[base + 1], vi = red[base + 2];
            if (v1 < M1)       { M2 = fminf(M1, v2); M1 = v1; I = vi; }
            else if (v1 == M1) { I = fminf(I, vi); M2 = fminf(M2, v1); M2 = fminf(M2, v2); }
            else               { M2 = fminf(M2, v1); }
        }
        int id = (int)I;
        bestIdx[n0 + th] = (M2 - M1 < MARGIN) ? (id | FLAGBIT) : id;
    }
}

// -------- fallback-path refine (FLAGBIT scan, unchanged semantics) --------
__global__ __launch_bounds__(64) void k_refine(const float* __restrict__ Z,
                                               const float* __restrict__ E,
                                               const float* __restrict__ e2,
                                               const float* __restrict__ z2,
                                               int* __restrict__ bestIdx) {
    __shared__ float zr[DD];
    const int l = threadIdx.x;
    for (int i = 0; i < 16; ++i) {
        int n = (blockIdx.x << 4) + i;
        if (!(bestIdx[n] & FLAGBIT)) continue;
        int b = n >> 10, hw = n & 1023;
        __syncthreads();
#pragma unroll
        for (int j = 0; j < 4; ++j)
            zr[(l << 2) + j] = Z[(size_t)((b << 8) + (l << 2) + j) * HWN + hw];
        __syncthreads();
        const float z2v = z2[n];
        float gbest = __builtin_inff();
        int bi = KK;
        for (int kk = 0; kk < 16; ++kk) {
            int k = (kk << 6) + l;
            double dot = 0.0;
            for (int d = 0; d < DD; d += 4) {
                float4 e4 = *reinterpret_cast<const float4*>(&E[(size_t)k * DD + d]);
                dot += (double)e4.x * zr[d]     + (double)e4.y * zr[d + 1]
                     + (double)e4.z * zr[d + 2] + (double)e4.w * zr[d + 3];
            }
            float c = (float)dot;
            float t = __fmul_rn(2.0f, c);
            float gg = __fsub_rn(__fadd_rn(z2v, e2[k]), t);
            if (gg < gbest) { gbest = gg; bi = k; }
        }
#pragma unroll
        for (int off = 32; off > 0; off >>= 1) {
            float og = __shfl_down(gbest, off);
            int oi = __shfl_down(bi, off);
            if (og < gbest || (og == gbest && oi < bi)) { gbest = og; bi = oi; }
        }
        if (l == 0) bestIdx[n] = bi;
    }
}

// ---- outputs (MFMA path): idx (FLAGBIT->bestG), loss from Zh, z_q staged ----
__global__ __launch_bounds__(256) void k_out(const ushort* __restrict__ Zh,
                                             const float* __restrict__ E,
                                             const int* __restrict__ bestIdx,
                                             const u64* __restrict__ bestG,
                                             float* __restrict__ out) {
    __shared__ int idxs[64];
    __shared__ float es[64][68];       // 17408 B staged E chunk
    const int th = threadIdx.x;
    const int n0 = blockIdx.x << 6;    // 512 blocks, 64 rows each
    const int b = n0 >> 10;
    const int hw0 = n0 & 1023;

    if (th < 64) {
        int n = n0 + th;
        int v = bestIdx[n];
        int id = (v & FLAGBIT) ? (int)(unsigned)(bestG[n] & 1023ull) : (v & 1023);
        idxs[th] = id;
        out[IDX_OFF + n] = (float)id;
    }
    __syncthreads();

    // loss (NHWC): lane-adjacent float4 writes; z from Zh (f16, err << threshold)
#pragma unroll
    for (int j = 0; j < 16; ++j) {
        int i4 = (j << 8) + th;        // 0..4095
        int r = i4 >> 6;               // 0..63
        int f = (i4 & 63) << 2;        // 0..252
        int n = n0 + r;
        float4 e4 = *reinterpret_cast<const float4*>(&E[(size_t)idxs[r] * DD + f]);
        ushort4 zu = *reinterpret_cast<const ushort4*>(&Zh[(size_t)n * DD + f]);
        float4 o;
        float t;
        t = e4.x - h2f(zu.x); o.x = t * t;
        t = e4.y - h2f(zu.y); o.y = t * t;
        t = e4.z - h2f(zu.z); o.z = t * t;
        t = e4.w - h2f(zu.w); o.w = t * t;
        *reinterpret_cast<float4*>(&out[LOSS_OFF + (size_t)n * DD + f]) = o;
    }

    // z_q (NCHW): stage gathered E rows per dc-chunk, write hw-coalesced
    for (int dc = 0; dc < 4; ++dc) {
        __syncthreads();               // protect es from previous dc's reads
        {
            const int r = th >> 2, qd = (th & 3) << 4;
            const float* er = &E[(size_t)idxs[r] * DD + (dc << 6) + qd];
#pragma unroll
            for (int v = 0; v < 4; ++v)
                *reinterpret_cast<float4*>(&es[r][qd + (v << 2)]) =
                    *reinterpret_cast<const float4*>(er + (v << 2));
        }
        __syncthreads();
#pragma unroll
        for (int j = 0; j < 16; ++j) {
            int li = (j << 8) + th;
            int dd = li >> 6;
            int r = li & 63;
            out[ZQ_OFF + (size_t)((b << 8) + (dc << 6) + dd) * HWN + hw0 + r] =
                es[r][dd];
        }
    }
}

// -------- outputs (fallback path): reads Z --------
__global__ __launch_bounds__(256) void k_out_f32(const float* __restrict__ Z,
                                                 const float* __restrict__ E,
                                                 const int* __restrict__ bestIdx,
                                                 float* __restrict__ out) {
    __shared__ float zc[64][68];
    __shared__ int idxs[64];
    const int th = threadIdx.x;
    const int n0 = blockIdx.x << 6;
    const int b = n0 >> 10;
    const int hw0 = n0 & 1023;

    if (th < 64) {
        int id = bestIdx[n0 + th] & 1023;
        idxs[th] = id;
        out[IDX_OFF + n0 + th] = (float)id;
    }
    __syncthreads();

    for (int dc = 0; dc < 4; ++dc) {
        __syncthreads();
#pragma unroll
        for (int j = 0; j < 16; ++j) {
            int li = (j << 8) + th;
            int dd = li >> 6;
            int r = li & 63;
            zc[r][dd] = Z[(size_t)((b << 8) + (dc << 6) + dd) * HWN + hw0 + r];
        }
        __syncthreads();
#pragma unroll
        for (int j = 0; j < 4; ++j) {
            int i4 = (j << 8) + th;
            int r = i4 >> 4;
            int f = (i4 & 15) << 2;
            float4 e4 = *reinterpret_cast<const float4*>(
                &E[(size_t)idxs[r] * DD + (dc << 6) + f]);
            float4 z4 = *reinterpret_cast<const float4*>(&zc[r][f]);
            float4 o;
            o.x = (e4.x - z4.x) * (e4.x - z4.x);
            o.y = (e4.y - z4.y) * (e4.y - z4.y);
            o.z = (e4.z - z4.z) * (e4.z - z4.z);
            o.w = (e4.w - z4.w) * (e4.w - z4.w);
            *reinterpret_cast<float4*>(
                &out[LOSS_OFF + (size_t)(n0 + r) * DD + (dc << 6) + f]) = o;
        }
#pragma unroll
        for (int j = 0; j < 16; ++j) {
            int li = (j << 8) + th;
            int dd = li >> 6;
            int r = li & 63;
            out[ZQ_OFF + (size_t)((b << 8) + (dc << 6) + dd) * HWN + hw0 + r] =
                E[(size_t)idxs[r] * DD + (dc << 6) + dd];
        }
    }
}

extern "C" void kernel_launch(void* const* d_in, const int* in_sizes, int n_in,
                              void* d_out, int out_size, void* d_ws, size_t ws_size,
                              hipStream_t stream) {
    const float* Z = (const float*)d_in[0];           // [32,256,32,32] f32
    const float* E = (const float*)d_in[1];           // [1024,256] f32
    float* out = (float*)d_out;
    char* ws = (char*)d_ws;
    float* e2 = (float*)ws;
    float* z2 = (float*)(ws + 4096);
    int* bestIdx = (int*)(ws + 135168);

    if (ws_size >= WS_NEED) {
        float* part = (float*)(ws + 266240);
        ushort* Eh = (ushort*)(ws + 3411968);
        ushort* Zh = (ushort*)(ws + 4460544);
        u64* bestG = (u64*)(ws + 21237760);
        int* flagCount = (int*)(ws + 38014976);
        int* flagList = (int*)(ws + 38015040);
        k_prepEf<<<32, 256, 0, stream>>>(E, Eh, e2, flagCount);
        k_prepZ2<<<1024, 256, 0, stream>>>(Z, Zh, z2);
        k_dist_mfma<<<2048, 256, 0, stream>>>(Zh, Eh, e2, part);
        k_combine<<<NN / 256, 256, 0, stream>>>(part, bestIdx, flagList, flagCount, bestG);
        k_refine5<<<2048, 256, 0, stream>>>(Z, E, e2, z2, flagList, flagCount, bestG);
        k_out<<<NN / 64, 256, 0, stream>>>(Zh, E, bestIdx, bestG, out);
    } else {
        k_e2<<<32, 256, 0, stream>>>(E, e2);
        k_z2<<<NN / 256, 256, 0, stream>>>(Z, z2);
        k_dist_f32<<<NN / 64, 256, 0, stream>>>(Z, E, e2, bestIdx);
        k_refine<<<NN / 16, 64, 0, stream>>>(Z, E, e2, z2, bestIdx);
        k_out_f32<<<NN / 64, 256, 0, stream>>>(Z, E, bestIdx, out);
    }
}